// Round 4
// baseline (999.810 us; speedup 1.0000x reference)
//
#include <hip/hip_runtime.h>
#include <hip/hip_bf16.h>
#include <cstdint>

#define N_NODES 100000
#define N_EDGES 800000
#define CH      256
#define COUT    40
#define COUTP   48
#define EPS     1e-5f
#define SCAN_CHUNK 1024
#define NSCAN_BLK  98   // ceil(100000/1024)
#define SB_NBLK 500
#define SB_ROWS 200     // 500*200 = 100000 exactly
#define NAGG_BLK 782    // ceil(100000/128)

typedef unsigned short u16;
typedef unsigned int   u32;
typedef short s16x8 __attribute__((ext_vector_type(8)));
typedef float f32x4 __attribute__((ext_vector_type(4)));

__device__ __forceinline__ float b2f(u32 u) { return __uint_as_float(u << 16); }
__device__ __forceinline__ u16 f2b(float f) {
    u32 u = __float_as_uint(f);
    u32 r = (u + 0x7fffu + ((u >> 16) & 1u)) >> 16;   // RNE
    return (u16)r;
}
__device__ __forceinline__ u32 packb(float a, float b) {
    return (u32)f2b(a) | ((u32)f2b(b) << 16);
}
__device__ __forceinline__ void unpack8(uint4 v, float* f) {
    f[0] = b2f(v.x & 0xffffu); f[1] = b2f(v.x >> 16);
    f[2] = b2f(v.y & 0xffffu); f[3] = b2f(v.y >> 16);
    f[4] = b2f(v.z & 0xffffu); f[5] = b2f(v.z >> 16);
    f[6] = b2f(v.w & 0xffffu); f[7] = b2f(v.w >> 16);
}

// ---------------- CSR build ----------------
__global__ void k_count(const int* __restrict__ dst, int* __restrict__ counts) {
    int e = blockIdx.x * 256 + threadIdx.x;
    if (e < N_EDGES) atomicAdd(&counts[dst[e]], 1);
}

__global__ void k_scan1(const int* __restrict__ counts, int* __restrict__ partial,
                        int* __restrict__ blocksums) {
    __shared__ int sdata[256];
    int base = blockIdx.x * SCAN_CHUNK;
    int t = threadIdx.x;
    int v[4]; int s = 0;
    for (int j = 0; j < 4; j++) {
        int i = base + t * 4 + j;
        v[j] = (i < N_NODES) ? counts[i] : 0;
        s += v[j];
    }
    sdata[t] = s; __syncthreads();
    for (int off = 1; off < 256; off <<= 1) {
        int x = (t >= off) ? sdata[t - off] : 0;
        __syncthreads();
        sdata[t] += x;
        __syncthreads();
    }
    int incl = sdata[t];
    int run = incl - s;
    if (t == 255) blocksums[blockIdx.x] = incl;
    for (int j = 0; j < 4; j++) {
        int i = base + t * 4 + j;
        if (i < N_NODES) partial[i] = run;
        run += v[j];
    }
}

__global__ void k_scan2(int* __restrict__ blocksums) {
    __shared__ int sd[128];
    int t = threadIdx.x;
    int v = (t < NSCAN_BLK) ? blocksums[t] : 0;
    sd[t] = v; __syncthreads();
    for (int off = 1; off < 128; off <<= 1) {
        int x = (t >= off) ? sd[t - off] : 0;
        __syncthreads();
        sd[t] += x;
        __syncthreads();
    }
    if (t < NSCAN_BLK) blocksums[t] = sd[t] - v;
}

__global__ void k_scan3(int* __restrict__ row_start, const int* __restrict__ blocksums,
                        int* __restrict__ cursor, const int* __restrict__ counts,
                        float* __restrict__ dis) {
    int i = blockIdx.x * 256 + threadIdx.x;
    if (i < N_NODES) {
        int v = row_start[i] + blocksums[i >> 10];
        row_start[i] = v;
        cursor[i] = v;
        dis[i] = rsqrtf(1.0f + (float)counts[i]);
    }
}

__global__ void k_fill(const int* __restrict__ src, const int* __restrict__ dst,
                       int* __restrict__ cursor, int* __restrict__ csr,
                       const float* __restrict__ dis, float* __restrict__ coefv) {
    int e = blockIdx.x * 256 + threadIdx.x;
    if (e < N_EDGES) {
        int d = dst[e], s = src[e];
        int p = atomicAdd(&cursor[d], 1);
        csr[p] = s;
        coefv[p] = dis[s] * dis[d];
    }
}

// ---------------- weight transpose (all 3) + bf16 convert ----------------
__global__ void k_wt3(const float* __restrict__ W0, const float* __restrict__ W1,
                      const float* __restrict__ W2,
                      u16* __restrict__ T0, u16* __restrict__ T1, u16* __restrict__ T2) {
    int b = blockIdx.x, k = threadIdx.x;
    if (b < 256) {
        T0[b * 256 + k] = f2b(W0[k * 256 + b]);
    } else if (b < 512) {
        int n = b - 256;
        T1[n * 256 + k] = f2b(W1[k * 256 + n]);
    } else {
        int n = b - 512;
        T2[n * 256 + k] = f2b(n < COUT ? W2[k * COUT + n] : 0.f);
    }
}

__global__ void k_xconv(const float* __restrict__ x, u16* __restrict__ xb) {
    int idx = (blockIdx.x * 256 + threadIdx.x) * 8;
    float4 a = *(const float4*)(x + idx);
    float4 b = *(const float4*)(x + idx + 4);
    uint4 o = {packb(a.x, a.y), packb(a.z, a.w), packb(b.x, b.y), packb(b.z, b.w)};
    *(uint4*)(xb + idx) = o;
}

// ---------------- tiny: outv[j] = sum_k vec[k] * W[k*ncols+j] ----------------
__global__ void k_vecmat(const float* __restrict__ vec, const float* __restrict__ W,
                         int ncols, int npad, float* __restrict__ outv) {
    __shared__ float s[256];
    int t = threadIdx.x;
    s[t] = vec[t];
    __syncthreads();
    float acc = 0.f;
    if (t < ncols) {
        for (int k = 0; k < 256; k++) acc += s[k] * W[k * ncols + t];
    }
    if (t < npad) outv[t] = acc;
}

// ---------------- GEMM: Hout[N,256] = A[N,256] @ W (bf16 MFMA) ----------------
__global__ __launch_bounds__(256) void k_gemm(const u16* __restrict__ A,
                                              const u16* __restrict__ Wt,
                                              u16* __restrict__ Hout) {
    __shared__ u16 Bs[256 * 40];
    const int t = threadIdx.x;
    const int wave = t >> 6, lane = t & 63;
    const int lm = lane & 15, quad = lane >> 4;
    const int m0 = blockIdx.x * 64;
    const f32x4 vz = {0.f, 0.f, 0.f, 0.f};
    f32x4 acc[4][4];
    for (int m = 0; m < 4; m++)
        for (int c = 0; c < 4; c++) acc[m][c] = vz;

    for (int k0 = 0; k0 < 256; k0 += 32) {
        {
            const uint4* srcp = (const uint4*)(Wt + t * 256 + k0);
            uint4* dl = (uint4*)(Bs + t * 40);
            dl[0] = srcp[0]; dl[1] = srcp[1]; dl[2] = srcp[2]; dl[3] = srcp[3];
        }
        __syncthreads();
        s16x8 afrag[4];
#pragma unroll
        for (int m = 0; m < 4; m++) {
            int row = m0 + m * 16 + lm;
            if (row < N_NODES) afrag[m] = *(const s16x8*)(A + (size_t)row * 256 + k0 + quad * 8);
            else { s16x8 z = {0,0,0,0,0,0,0,0}; afrag[m] = z; }
        }
#pragma unroll
        for (int c = 0; c < 4; c++) {
            s16x8 bfrag = *(const s16x8*)(Bs + (wave * 64 + c * 16 + lm) * 40 + quad * 8);
#pragma unroll
            for (int m = 0; m < 4; m++)
                acc[m][c] = __builtin_amdgcn_mfma_f32_16x16x32_bf16(afrag[m], bfrag, acc[m][c], 0, 0, 0);
        }
        __syncthreads();
    }
#pragma unroll
    for (int m = 0; m < 4; m++) {
#pragma unroll
        for (int c = 0; c < 4; c++) {
            int col = wave * 64 + c * 16 + lm;
#pragma unroll
            for (int i = 0; i < 4; i++) {
                int row = m0 + m * 16 + quad * 4 + i;
                if (row < N_NODES) Hout[(size_t)row * 256 + col] = f2b(acc[m][c][i]);
            }
        }
    }
}

// ---------------- GEMM layer 2: Hout[N,48] = A[N,256] @ W2pad ----------------
__global__ __launch_bounds__(256) void k_gemm2(const u16* __restrict__ A,
                                               const u16* __restrict__ Wt,
                                               u16* __restrict__ Hout) {
    __shared__ u16 Bs[48 * 40];
    const int t = threadIdx.x;
    const int wave = t >> 6, lane = t & 63;
    const int lm = lane & 15, quad = lane >> 4;
    const int m0 = blockIdx.x * 64;
    const f32x4 vz = {0.f, 0.f, 0.f, 0.f};
    f32x4 acc[3]; acc[0] = vz; acc[1] = vz; acc[2] = vz;

    for (int k0 = 0; k0 < 256; k0 += 32) {
        if (t < 48) {
            const uint4* srcp = (const uint4*)(Wt + t * 256 + k0);
            uint4* dl = (uint4*)(Bs + t * 40);
            dl[0] = srcp[0]; dl[1] = srcp[1]; dl[2] = srcp[2]; dl[3] = srcp[3];
        }
        __syncthreads();
        int row = m0 + wave * 16 + lm;
        s16x8 af;
        if (row < N_NODES) af = *(const s16x8*)(A + (size_t)row * 256 + k0 + quad * 8);
        else { s16x8 z = {0,0,0,0,0,0,0,0}; af = z; }
#pragma unroll
        for (int c = 0; c < 3; c++) {
            s16x8 bf = *(const s16x8*)(Bs + (c * 16 + lm) * 40 + quad * 8);
            acc[c] = __builtin_amdgcn_mfma_f32_16x16x32_bf16(af, bf, acc[c], 0, 0, 0);
        }
        __syncthreads();
    }
#pragma unroll
    for (int c = 0; c < 3; c++) {
        int col = c * 16 + lm;
#pragma unroll
        for (int i = 0; i < 4; i++) {
            int row = m0 + wave * 16 + quad * 4 + i;
            if (row < N_NODES) Hout[(size_t)row * COUTP + col] = f2b(acc[c][i]);
        }
    }
}

// ---- sliced aggregation: 64-channel pass (ci0 = 0/64/128/192), fused BN stats ----
// 8 lanes/node (uint4 = 8 ch/lane), 8 node-groups/wave, 4 nodes/group. grid = 782
__global__ __launch_bounds__(256) void k_agg(const u16* __restrict__ H2,
                                             const int* __restrict__ row_start,
                                             const int* __restrict__ counts,
                                             const int* __restrict__ csr,
                                             const float* __restrict__ coefv,
                                             const float* __restrict__ dis,
                                             const float* __restrict__ bias,
                                             const float* __restrict__ v2,
                                             u16* __restrict__ OutB,
                                             float* __restrict__ stats,
                                             int ci0) {
    __shared__ float ls[128];
    const int t = threadIdx.x, wave = t >> 6, lane = t & 63;
    const int grp = lane >> 3, gl = lane & 7;
    const int ci = ci0 + gl * 8;
    float bb[8], vv[8];
    {
        float4 a = *(const float4*)(bias + ci);
        float4 b = *(const float4*)(bias + ci + 4);
        float4 c = *(const float4*)(v2 + ci);
        float4 d = *(const float4*)(v2 + ci + 4);
        bb[0]=a.x; bb[1]=a.y; bb[2]=a.z; bb[3]=a.w; bb[4]=b.x; bb[5]=b.y; bb[6]=b.z; bb[7]=b.w;
        vv[0]=c.x; vv[1]=c.y; vv[2]=c.z; vv[3]=c.w; vv[4]=d.x; vv[5]=d.y; vv[6]=d.z; vv[7]=d.w;
    }
    float s[8], q[8];
#pragma unroll
    for (int j = 0; j < 8; j++) { s[j] = 0.f; q[j] = 0.f; }
    const int nbase = blockIdx.x * 128 + wave * 32 + grp * 4;
    for (int i = 0; i < 4; i++) {
        const int node = nbase + i;
        if (node >= N_NODES) break;
        const int beg = row_start[node], cnt = counts[node];
        const float dn = dis[node];
        float a[8];
#pragma unroll
        for (int j = 0; j < 8; j++) a[j] = 0.f;
        float cs = 0.f;
        int e = 0;
        for (; e + 2 <= cnt; e += 2) {
            int ia = csr[beg + e], ib = csr[beg + e + 1];
            float ca = coefv[beg + e], cb = coefv[beg + e + 1];
            uint4 ra = *(const uint4*)(H2 + (size_t)ia * 256 + ci);
            uint4 rb = *(const uint4*)(H2 + (size_t)ib * 256 + ci);
            cs += ca + cb;
            float fa[8], fb[8]; unpack8(ra, fa); unpack8(rb, fb);
#pragma unroll
            for (int j = 0; j < 8; j++) a[j] += ca * fa[j] + cb * fb[j];
        }
        if (e < cnt) {
            int ia = csr[beg + e]; float ca = coefv[beg + e];
            uint4 ra = *(const uint4*)(H2 + (size_t)ia * 256 + ci);
            cs += ca;
            float fa[8]; unpack8(ra, fa);
#pragma unroll
            for (int j = 0; j < 8; j++) a[j] += ca * fa[j];
        }
        uint4 rs = *(const uint4*)(H2 + (size_t)node * 256 + ci);
        float fs[8]; unpack8(rs, fs);
        const float sc = dn * dn, cv = cs + sc;
        float f[8];
#pragma unroll
        for (int j = 0; j < 8; j++) {
            f[j] = a[j] + sc * fs[j] + cv * vv[j] + bb[j];
            s[j] += f[j]; q[j] += f[j] * f[j];
        }
        uint4 o = {packb(f[0], f[1]), packb(f[2], f[3]), packb(f[4], f[5]), packb(f[6], f[7])};
        *(uint4*)(OutB + (size_t)node * 256 + ci) = o;
    }
    if (t < 128) ls[t] = 0.f;
    __syncthreads();
    const int li = gl * 8;
#pragma unroll
    for (int j = 0; j < 8; j++) {
        atomicAdd(&ls[li + j], s[j]);
        atomicAdd(&ls[64 + li + j], q[j]);
    }
    __syncthreads();
    if (t < 64) atomicAdd(&stats[ci0 + t], ls[t]);
    else if (t < 128) atomicAdd(&stats[256 + ci0 + (t - 64)], ls[t]);
}

// ---------------- BN apply + ReLU + pool (inline BN finalize) ----------------
__global__ __launch_bounds__(256) void k_bnrelu(const u16* __restrict__ OutB,
                                                const float* __restrict__ stats,
                                                const float* __restrict__ g,
                                                const float* __restrict__ bb_,
                                                u16* __restrict__ Hr,
                                                float* __restrict__ pool) {
    __shared__ float lp[256];
    const int t = threadIdx.x;
    const int cg = (t & 31) * 8;
    const int rg = t >> 5;
    const int r0 = blockIdx.x * SB_ROWS + rg;
    const float inv = 1.0f / (float)N_NODES;
    float gg[8], bc[8];
#pragma unroll
    for (int j = 0; j < 8; j++) {
        int c = cg + j;
        float mu = stats[c] * inv;
        float var = stats[256 + c] * inv - mu * mu;
        float rs = rsqrtf(var + EPS);
        gg[j] = g[c] * rs;
        bc[j] = bb_[c] - mu * gg[j];
    }
    float ps[8];
#pragma unroll
    for (int j = 0; j < 8; j++) ps[j] = 0.f;
#pragma unroll 2
    for (int it = 0; it < SB_ROWS / 8; it++) {
        int r = r0 + it * 8;
        uint4 v = *(const uint4*)(OutB + (size_t)r * 256 + cg);
        float f[8]; unpack8(v, f);
#pragma unroll
        for (int j = 0; j < 8; j++) {
            f[j] = fmaxf(f[j] * gg[j] + bc[j], 0.f);
            ps[j] += f[j];
        }
        uint4 o = {packb(f[0], f[1]), packb(f[2], f[3]), packb(f[4], f[5]), packb(f[6], f[7])};
        *(uint4*)(Hr + (size_t)r * 256 + cg) = o;
    }
    lp[t] = 0.f;
    __syncthreads();
#pragma unroll
    for (int j = 0; j < 8; j++) atomicAdd(&lp[cg + j], ps[j]);
    __syncthreads();
    atomicAdd(&pool[t], lp[t]);
}

// ---------------- virtual node update + v2_next = vx_new @ Wnext ----------------
__global__ void k_vx(const float* __restrict__ pool, const float* __restrict__ vx_old,
                     const float* __restrict__ vnW, const float* __restrict__ vnb,
                     const float* __restrict__ lng, const float* __restrict__ lnb,
                     float* __restrict__ vx_new,
                     const float* __restrict__ Wnext, int ncn, int npn,
                     float* __restrict__ v2n) {
    __shared__ float s[256];
    __shared__ float red[256];
    int t = threadIdx.x;
    s[t] = pool[t] + vx_old[t];
    __syncthreads();
    float y = vnb[t];
    for (int k = 0; k < 256; k++) y += s[k] * vnW[k * 256 + t];
    red[t] = y; __syncthreads();
    for (int off = 128; off > 0; off >>= 1) {
        if (t < off) red[t] += red[t + off];
        __syncthreads();
    }
    float mu = red[0] * (1.f / 256.f);
    __syncthreads();
    float d = y - mu;
    red[t] = d * d; __syncthreads();
    for (int off = 128; off > 0; off >>= 1) {
        if (t < off) red[t] += red[t + off];
        __syncthreads();
    }
    float var = red[0] * (1.f / 256.f);
    float v = fmaxf(d * rsqrtf(var + EPS) * lng[t] + lnb[t], 0.f);
    vx_new[t] = v;
    __syncthreads();
    s[t] = v;
    __syncthreads();
    float acc = 0.f;
    if (t < ncn) {
        for (int k = 0; k < 256; k++) acc += s[k] * Wnext[k * ncn + t];
    }
    if (t < npn) v2n[t] = acc;
}

// ---- layer-2 aggregation + (cs+dn^2)*v2 fold + log_softmax ----
__global__ __launch_bounds__(256) void k_agg2(const u16* __restrict__ H2,
                                              const int* __restrict__ row_start,
                                              const int* __restrict__ counts,
                                              const int* __restrict__ csr,
                                              const float* __restrict__ coefv,
                                              const float* __restrict__ dis,
                                              const float* __restrict__ bias,
                                              const float* __restrict__ v2,
                                              float* __restrict__ OutF) {
    const int t = threadIdx.x, wave = t >> 6, lane = t & 63;
    const int half = lane >> 5, hl = lane & 31;
    const bool gact = hl < 24;   // gather lanes (48 padded channels, 2/lane)
    const bool cact = hl < 20;   // real channel pairs (40)
    const int c0 = 2 * hl;
    float bb0 = 0.f, bb1 = 0.f, vv0 = 0.f, vv1 = 0.f;
    if (cact) {
        float2 bv = *(const float2*)(bias + c0); bb0 = bv.x; bb1 = bv.y;
        float2 vvv = *(const float2*)(v2 + c0);  vv0 = vvv.x; vv1 = vvv.y;
    }
    const int nbase = blockIdx.x * 16 + wave * 4;
    for (int i = 0; i < 4; i++) {
        const int node = nbase + i;
        const int beg = row_start[node], cnt = counts[node];
        const float dn = dis[node];
        float a0 = 0.f, a1 = 0.f, cs = 0.f;
        int e = half;
        for (; e + 6 < cnt; e += 8) {
            int ia = csr[beg+e], ib = csr[beg+e+2], ic = csr[beg+e+4], id = csr[beg+e+6];
            float ca = coefv[beg+e], cb = coefv[beg+e+2], cc = coefv[beg+e+4], cd = coefv[beg+e+6];
            u32 ra = 0, rb = 0, rc = 0, rd = 0;
            if (gact) {
                ra = *(const u32*)(H2 + (size_t)ia * COUTP + c0);
                rb = *(const u32*)(H2 + (size_t)ib * COUTP + c0);
                rc = *(const u32*)(H2 + (size_t)ic * COUTP + c0);
                rd = *(const u32*)(H2 + (size_t)id * COUTP + c0);
            }
            cs += ca + cb + cc + cd;
            a0 += ca*b2f(ra&0xffffu) + cb*b2f(rb&0xffffu) + cc*b2f(rc&0xffffu) + cd*b2f(rd&0xffffu);
            a1 += ca*b2f(ra>>16)     + cb*b2f(rb>>16)     + cc*b2f(rc>>16)     + cd*b2f(rd>>16);
        }
        for (; e < cnt; e += 2) {
            int ia = csr[beg+e]; float ca = coefv[beg+e];
            u32 ra = gact ? *(const u32*)(H2 + (size_t)ia * COUTP + c0) : 0u;
            cs += ca;
            a0 += ca*b2f(ra&0xffffu); a1 += ca*b2f(ra>>16);
        }
        a0 += __shfl_xor(a0, 32);
        a1 += __shfl_xor(a1, 32);
        cs += __shfl_xor(cs, 32);
        const float sc = dn * dn;
        u32 rs_ = gact ? *(const u32*)(H2 + (size_t)node * COUTP + c0) : 0u;
        float h0 = a0 + sc*b2f(rs_&0xffffu) + (cs+sc)*vv0 + bb0;
        float h1 = a1 + sc*b2f(rs_>>16)     + (cs+sc)*vv1 + bb1;
        float m = cact ? fmaxf(h0, h1) : -3.0e38f;
#pragma unroll
        for (int off = 16; off > 0; off >>= 1) m = fmaxf(m, __shfl_xor(m, off));
        float ex = cact ? (expf(h0 - m) + expf(h1 - m)) : 0.f;
        float se = ex;
#pragma unroll
        for (int off = 16; off > 0; off >>= 1) se += __shfl_xor(se, off);
        float lg = logf(se);
        if (cact && half == 0) {
            float2 o = {h0 - m - lg, h1 - m - lg};
            *(float2*)(OutF + (size_t)node * COUT + c0) = o;
        }
    }
}

extern "C" void kernel_launch(void* const* d_in, const int* in_sizes, int n_in,
                              void* d_out, int out_size, void* d_ws, size_t ws_size,
                              hipStream_t stream) {
    const float* x   = (const float*)d_in[0];
    const int*   ei  = (const int*)d_in[1];
    const int*   esrc = ei;
    const int*   edst = ei + N_EDGES;
    const float* W0 = (const float*)d_in[2];  const float* b0 = (const float*)d_in[3];
    const float* W1 = (const float*)d_in[4];  const float* b1 = (const float*)d_in[5];
    const float* W2 = (const float*)d_in[6];  const float* b2 = (const float*)d_in[7];
    const float* bg0 = (const float*)d_in[8]; const float* bb0 = (const float*)d_in[9];
    const float* bg1 = (const float*)d_in[10]; const float* bb1 = (const float*)d_in[11];
    const float* vn_emb = (const float*)d_in[12];
    const float* vW0 = (const float*)d_in[13]; const float* vb0 = (const float*)d_in[14];
    const float* lg0 = (const float*)d_in[15]; const float* lb0 = (const float*)d_in[16];
    const float* vW1 = (const float*)d_in[17]; const float* vb1 = (const float*)d_in[18];
    const float* lg1 = (const float*)d_in[19]; const float* lb1 = (const float*)d_in[20];

    char* w = (char*)d_ws;
    auto alloc = [&](size_t bytes) { void* p = (void*)w; w += ((bytes + 255) / 256) * 256; return p; };
    u16* H2    = (u16*)alloc((size_t)N_NODES * 256 * 2);
    u16* HR    = (u16*)alloc((size_t)N_NODES * 256 * 2);
    u16* OutB  = (u16*)alloc((size_t)N_NODES * 256 * 2);
    int* csr   = (int*)alloc((size_t)N_EDGES * 4);
    float* coefv = (float*)alloc((size_t)N_EDGES * 4);
    int* counts = (int*)alloc((size_t)N_NODES * 4);
    int* rowst  = (int*)alloc((size_t)N_NODES * 4);
    int* cursor = (int*)alloc((size_t)N_NODES * 4);
    float* dis  = (float*)alloc((size_t)N_NODES * 4);
    u16* Wtb0 = (u16*)alloc(256 * 256 * 2);
    u16* Wtb1 = (u16*)alloc(256 * 256 * 2);
    u16* Wt2b = (u16*)alloc(COUTP * 256 * 2);
    int* scanblk = (int*)alloc(128 * 4);
    float* stats = (float*)alloc(768 * 4);   // sum[256], sumsq[256], pool[256]
    float* vxA = (float*)alloc(256 * 4);
    float* vxB = (float*)alloc(256 * 4);
    float* v20 = (float*)alloc(256 * 4);
    float* v21 = (float*)alloc(256 * 4);
    float* v22 = (float*)alloc(64 * 4);
    (void)ws_size; (void)in_sizes; (void)n_in; (void)out_size; (void)vxB;

    // ---- graph prep: degrees + CSR + edge coefficients ----
    hipMemsetAsync(counts, 0, (size_t)N_NODES * 4, stream);
    k_count<<<(N_EDGES + 255) / 256, 256, 0, stream>>>(edst, counts);
    k_scan1<<<NSCAN_BLK, 256, 0, stream>>>(counts, rowst, scanblk);
    k_scan2<<<1, 128, 0, stream>>>(scanblk);
    k_scan3<<<(N_NODES + 255) / 256, 256, 0, stream>>>(rowst, scanblk, cursor, counts, dis);
    k_fill<<<(N_EDGES + 255) / 256, 256, 0, stream>>>(esrc, edst, cursor, csr, dis, coefv);

    // ---- weight prep ----
    k_wt3<<<512 + COUTP, 256, 0, stream>>>(W0, W1, W2, Wtb0, Wtb1, Wt2b);
    k_xconv<<<(N_NODES * 256 / 8 + 255) / 256, 256, 0, stream>>>(x, HR);
    k_vecmat<<<1, 256, 0, stream>>>(vn_emb, W0, 256, 256, v20);

    // ---- layer 0 ----
    k_gemm<<<(N_NODES + 63) / 64, 256, 0, stream>>>(HR, Wtb0, H2);
    hipMemsetAsync(stats, 0, 768 * 4, stream);
    for (int p = 0; p < 4; p++)
        k_agg<<<NAGG_BLK, 256, 0, stream>>>(H2, rowst, counts, csr, coefv, dis, b0, v20, OutB, stats, p * 64);
    k_bnrelu<<<SB_NBLK, 256, 0, stream>>>(OutB, stats, bg0, bb0, HR, stats + 512);
    k_vx<<<1, 256, 0, stream>>>(stats + 512, vn_emb, vW0, vb0, lg0, lb0, vxA, W1, 256, 256, v21);

    // ---- layer 1 ----
    k_gemm<<<(N_NODES + 63) / 64, 256, 0, stream>>>(HR, Wtb1, H2);
    hipMemsetAsync(stats, 0, 768 * 4, stream);
    for (int p = 0; p < 4; p++)
        k_agg<<<NAGG_BLK, 256, 0, stream>>>(H2, rowst, counts, csr, coefv, dis, b1, v21, OutB, stats, p * 64);
    k_bnrelu<<<SB_NBLK, 256, 0, stream>>>(OutB, stats, bg1, bb1, HR, stats + 512);
    k_vx<<<1, 256, 0, stream>>>(stats + 512, vxA, vW1, vb1, lg1, lb1, vxB, W2, COUT, COUTP, v22);

    // ---- layer 2 + log_softmax ----
    k_gemm2<<<(N_NODES + 63) / 64, 256, 0, stream>>>(HR, Wt2b, H2);
    k_agg2<<<N_NODES / 16, 256, 0, stream>>>(H2, rowst, counts, csr, coefv, dis, b2, v22, (float*)d_out);
}

// Round 5
// 785.894 us; speedup vs baseline: 1.2722x; 1.2722x over previous
//
#include <hip/hip_runtime.h>
#include <hip/hip_bf16.h>
#include <cstdint>

#define N_NODES 100000
#define N_EDGES 800000
#define CH      256
#define COUT    40
#define COUTP   48
#define EPS     1e-5f
#define SCAN_CHUNK 1024
#define NSCAN_BLK  98   // ceil(100000/1024)
#define SB_NBLK 500
#define SB_ROWS 200     // 500*200 = 100000 exactly
#define AGG_NPW 16      // nodes per wave in k_agg

typedef unsigned short u16;
typedef unsigned int   u32;
typedef short s16x8 __attribute__((ext_vector_type(8)));
typedef float f32x4 __attribute__((ext_vector_type(4)));

__device__ __forceinline__ float b2f(u32 u) { return __uint_as_float(u << 16); }
__device__ __forceinline__ u16 f2b(float f) {
    u32 u = __float_as_uint(f);
    u32 r = (u + 0x7fffu + ((u >> 16) & 1u)) >> 16;   // RNE
    return (u16)r;
}
__device__ __forceinline__ u32 packb(float a, float b) {
    return (u32)f2b(a) | ((u32)f2b(b) << 16);
}
__device__ __forceinline__ void unpack8(uint4 v, float* f) {
    f[0] = b2f(v.x & 0xffffu); f[1] = b2f(v.x >> 16);
    f[2] = b2f(v.y & 0xffffu); f[3] = b2f(v.y >> 16);
    f[4] = b2f(v.z & 0xffffu); f[5] = b2f(v.z >> 16);
    f[6] = b2f(v.w & 0xffffu); f[7] = b2f(v.w >> 16);
}

// ---------------- CSR build ----------------
__global__ void k_count(const int* __restrict__ dst, int* __restrict__ counts) {
    int e = blockIdx.x * 256 + threadIdx.x;
    if (e < N_EDGES) atomicAdd(&counts[dst[e]], 1);
}

__global__ void k_scan1(const int* __restrict__ counts, int* __restrict__ partial,
                        int* __restrict__ blocksums) {
    __shared__ int sdata[256];
    int base = blockIdx.x * SCAN_CHUNK;
    int t = threadIdx.x;
    int v[4]; int s = 0;
    for (int j = 0; j < 4; j++) {
        int i = base + t * 4 + j;
        v[j] = (i < N_NODES) ? counts[i] : 0;
        s += v[j];
    }
    sdata[t] = s; __syncthreads();
    for (int off = 1; off < 256; off <<= 1) {
        int x = (t >= off) ? sdata[t - off] : 0;
        __syncthreads();
        sdata[t] += x;
        __syncthreads();
    }
    int incl = sdata[t];
    int run = incl - s;
    if (t == 255) blocksums[blockIdx.x] = incl;
    for (int j = 0; j < 4; j++) {
        int i = base + t * 4 + j;
        if (i < N_NODES) partial[i] = run;
        run += v[j];
    }
}

__global__ void k_scan2(int* __restrict__ blocksums) {
    __shared__ int sd[128];
    int t = threadIdx.x;
    int v = (t < NSCAN_BLK) ? blocksums[t] : 0;
    sd[t] = v; __syncthreads();
    for (int off = 1; off < 128; off <<= 1) {
        int x = (t >= off) ? sd[t - off] : 0;
        __syncthreads();
        sd[t] += x;
        __syncthreads();
    }
    if (t < NSCAN_BLK) blocksums[t] = sd[t] - v;
}

__global__ void k_scan3(int* __restrict__ row_start, const int* __restrict__ blocksums,
                        int* __restrict__ cursor, const int* __restrict__ counts,
                        float* __restrict__ dis) {
    int i = blockIdx.x * 256 + threadIdx.x;
    if (i < N_NODES) {
        int v = row_start[i] + blocksums[i >> 10];
        row_start[i] = v;
        cursor[i] = v;
        dis[i] = rsqrtf(1.0f + (float)counts[i]);
    }
}

__global__ void k_fill(const int* __restrict__ src, const int* __restrict__ dst,
                       int* __restrict__ cursor, int* __restrict__ csr,
                       const float* __restrict__ dis, float* __restrict__ coefv) {
    int e = blockIdx.x * 256 + threadIdx.x;
    if (e < N_EDGES) {
        int d = dst[e], s = src[e];
        int p = atomicAdd(&cursor[d], 1);
        csr[p] = s;
        coefv[p] = dis[s] * dis[d];
    }
}

// ---------------- weight transpose (all 3) + bf16 convert ----------------
__global__ void k_wt3(const float* __restrict__ W0, const float* __restrict__ W1,
                      const float* __restrict__ W2,
                      u16* __restrict__ T0, u16* __restrict__ T1, u16* __restrict__ T2) {
    int b = blockIdx.x, k = threadIdx.x;
    if (b < 256) {
        T0[b * 256 + k] = f2b(W0[k * 256 + b]);
    } else if (b < 512) {
        int n = b - 256;
        T1[n * 256 + k] = f2b(W1[k * 256 + n]);
    } else {
        int n = b - 512;
        T2[n * 256 + k] = f2b(n < COUT ? W2[k * COUT + n] : 0.f);
    }
}

__global__ void k_xconv(const float* __restrict__ x, u16* __restrict__ xb) {
    int idx = (blockIdx.x * 256 + threadIdx.x) * 8;
    float4 a = *(const float4*)(x + idx);
    float4 b = *(const float4*)(x + idx + 4);
    uint4 o = {packb(a.x, a.y), packb(a.z, a.w), packb(b.x, b.y), packb(b.z, b.w)};
    *(uint4*)(xb + idx) = o;
}

// ---------------- tiny: outv[j] = sum_k vec[k] * W[k*ncols+j] ----------------
__global__ void k_vecmat(const float* __restrict__ vec, const float* __restrict__ W,
                         int ncols, int npad, float* __restrict__ outv) {
    __shared__ float s[256];
    int t = threadIdx.x;
    s[t] = vec[t];
    __syncthreads();
    float acc = 0.f;
    if (t < ncols) {
        for (int k = 0; k < 256; k++) acc += s[k] * W[k * ncols + t];
    }
    if (t < npad) outv[t] = acc;
}

// ---------------- GEMM: Hout[N,256] = A[N,256] @ W (bf16 MFMA) ----------------
// M-tile 64, K-step 64, both A and B staged in LDS via coalesced loads.
__global__ __launch_bounds__(256) void k_gemm(const u16* __restrict__ A,
                                              const u16* __restrict__ Wt,
                                              u16* __restrict__ Hout) {
    __shared__ u16 Bs[256 * 72];   // 36 KB: 256 n-rows x (64+8) k
    __shared__ u16 As[64 * 72];    //  9 KB: 64 m-rows x (64+8) k
    const int t = threadIdx.x;
    const int wave = t >> 6, lane = t & 63;
    const int lm = lane & 15, quad = lane >> 4;
    const int m0 = blockIdx.x * 64;
    const int ar = t >> 2, as_ = (t & 3) * 16;   // A staging: 4 thr/row, 32 B each
    const int arow = m0 + ar;
    const f32x4 vz = {0.f, 0.f, 0.f, 0.f};
    f32x4 acc[4][4];
    for (int m = 0; m < 4; m++)
        for (int c = 0; c < 4; c++) acc[m][c] = vz;

    for (int k0 = 0; k0 < 256; k0 += 64) {
        {
            const uint4* bsrc = (const uint4*)(Wt + t * 256 + k0);
            uint4* bdst = (uint4*)(Bs + t * 72);
#pragma unroll
            for (int j = 0; j < 8; j++) bdst[j] = bsrc[j];
            uint4 a0v = {0,0,0,0}, a1v = {0,0,0,0};
            if (arow < N_NODES) {
                const uint4* asrc = (const uint4*)(A + (size_t)arow * 256 + k0 + as_);
                a0v = asrc[0]; a1v = asrc[1];
            }
            uint4* adst = (uint4*)(As + ar * 72 + as_);
            adst[0] = a0v; adst[1] = a1v;
        }
        __syncthreads();
#pragma unroll
        for (int kk = 0; kk < 64; kk += 32) {
            s16x8 af[4], bf[4];
#pragma unroll
            for (int m = 0; m < 4; m++)
                af[m] = *(const s16x8*)(As + (m * 16 + lm) * 72 + kk + quad * 8);
#pragma unroll
            for (int c = 0; c < 4; c++)
                bf[c] = *(const s16x8*)(Bs + (wave * 64 + c * 16 + lm) * 72 + kk + quad * 8);
#pragma unroll
            for (int c = 0; c < 4; c++)
#pragma unroll
                for (int m = 0; m < 4; m++)
                    acc[m][c] = __builtin_amdgcn_mfma_f32_16x16x32_bf16(af[m], bf[c], acc[m][c], 0, 0, 0);
        }
        __syncthreads();
    }
#pragma unroll
    for (int m = 0; m < 4; m++) {
#pragma unroll
        for (int c = 0; c < 4; c++) {
            int col = wave * 64 + c * 16 + lm;
#pragma unroll
            for (int i = 0; i < 4; i++) {
                int row = m0 + m * 16 + quad * 4 + i;
                if (row < N_NODES) Hout[(size_t)row * 256 + col] = f2b(acc[m][c][i]);
            }
        }
    }
}

// ---------------- GEMM layer 2: Hout[N,48] = A[N,256] @ W2pad ----------------
__global__ __launch_bounds__(256) void k_gemm2(const u16* __restrict__ A,
                                               const u16* __restrict__ Wt,
                                               u16* __restrict__ Hout) {
    __shared__ u16 Bs[48 * 72];
    __shared__ u16 As[64 * 72];
    const int t = threadIdx.x;
    const int wave = t >> 6, lane = t & 63;
    const int lm = lane & 15, quad = lane >> 4;
    const int m0 = blockIdx.x * 64;
    const int ar = t >> 2, as_ = (t & 3) * 16;
    const int arow = m0 + ar;
    const f32x4 vz = {0.f, 0.f, 0.f, 0.f};
    f32x4 acc[3]; acc[0] = vz; acc[1] = vz; acc[2] = vz;

    for (int k0 = 0; k0 < 256; k0 += 64) {
        {
            if (t < 48) {
                const uint4* bsrc = (const uint4*)(Wt + t * 256 + k0);
                uint4* bdst = (uint4*)(Bs + t * 72);
#pragma unroll
                for (int j = 0; j < 8; j++) bdst[j] = bsrc[j];
            }
            uint4 a0v = {0,0,0,0}, a1v = {0,0,0,0};
            if (arow < N_NODES) {
                const uint4* asrc = (const uint4*)(A + (size_t)arow * 256 + k0 + as_);
                a0v = asrc[0]; a1v = asrc[1];
            }
            uint4* adst = (uint4*)(As + ar * 72 + as_);
            adst[0] = a0v; adst[1] = a1v;
        }
        __syncthreads();
#pragma unroll
        for (int kk = 0; kk < 64; kk += 32) {
            s16x8 af = *(const s16x8*)(As + (wave * 16 + lm) * 72 + kk + quad * 8);
#pragma unroll
            for (int c = 0; c < 3; c++) {
                s16x8 bf = *(const s16x8*)(Bs + (c * 16 + lm) * 72 + kk + quad * 8);
                acc[c] = __builtin_amdgcn_mfma_f32_16x16x32_bf16(af, bf, acc[c], 0, 0, 0);
            }
        }
        __syncthreads();
    }
#pragma unroll
    for (int c = 0; c < 3; c++) {
        int col = c * 16 + lm;
#pragma unroll
        for (int i = 0; i < 4; i++) {
            int row = m0 + wave * 16 + quad * 4 + i;
            if (row < N_NODES) Hout[(size_t)row * COUTP + col] = f2b(acc[c][i]);
        }
    }
}

// ---- aggregation L0/L1 (monolithic, round-3 structure): fused v2 fold + BN stats ----
// 16 nodes/wave, 4-way edge unroll. grid = ceil(N/64)
__global__ __launch_bounds__(256) void k_agg(const u16* __restrict__ H2,
                                             const int* __restrict__ row_start,
                                             const int* __restrict__ counts,
                                             const int* __restrict__ csr,
                                             const float* __restrict__ coefv,
                                             const float* __restrict__ dis,
                                             const float* __restrict__ bias,
                                             const float* __restrict__ v2,
                                             u16* __restrict__ OutB,
                                             float* __restrict__ stats) {
    __shared__ float ls[512];
    const int t = threadIdx.x, wave = t >> 6, lane = t & 63, ci = lane * 4;
    const float4 bb = *(const float4*)(bias + ci);
    const float4 vv = *(const float4*)(v2 + ci);
    float s0=0,s1=0,s2=0,s3=0,q0=0,q1=0,q2=0,q3=0;
    const int nbase = blockIdx.x * (4 * AGG_NPW) + wave * AGG_NPW;
    for (int i = 0; i < AGG_NPW; i++) {
        const int node = nbase + i;
        if (node >= N_NODES) break;
        const int beg = row_start[node], cnt = counts[node];
        const float dn = dis[node];
        float a0=0,a1=0,a2=0,a3=0, cs=0;
        int e = 0;
        for (; e + 4 <= cnt; e += 4) {
            int ia = csr[beg+e], ib = csr[beg+e+1], ic = csr[beg+e+2], id = csr[beg+e+3];
            float ca = coefv[beg+e], cb = coefv[beg+e+1], cc = coefv[beg+e+2], cd = coefv[beg+e+3];
            uint2 ra = *(const uint2*)(H2 + (size_t)ia * 256 + ci);
            uint2 rb = *(const uint2*)(H2 + (size_t)ib * 256 + ci);
            uint2 rc = *(const uint2*)(H2 + (size_t)ic * 256 + ci);
            uint2 rd = *(const uint2*)(H2 + (size_t)id * 256 + ci);
            cs += ca + cb + cc + cd;
            a0 += ca*b2f(ra.x&0xffffu) + cb*b2f(rb.x&0xffffu) + cc*b2f(rc.x&0xffffu) + cd*b2f(rd.x&0xffffu);
            a1 += ca*b2f(ra.x>>16)     + cb*b2f(rb.x>>16)     + cc*b2f(rc.x>>16)     + cd*b2f(rd.x>>16);
            a2 += ca*b2f(ra.y&0xffffu) + cb*b2f(rb.y&0xffffu) + cc*b2f(rc.y&0xffffu) + cd*b2f(rd.y&0xffffu);
            a3 += ca*b2f(ra.y>>16)     + cb*b2f(rb.y>>16)     + cc*b2f(rc.y>>16)     + cd*b2f(rd.y>>16);
        }
        for (; e < cnt; e++) {
            int ia = csr[beg+e]; float ca = coefv[beg+e];
            uint2 ra = *(const uint2*)(H2 + (size_t)ia * 256 + ci);
            cs += ca;
            a0 += ca*b2f(ra.x&0xffffu); a1 += ca*b2f(ra.x>>16);
            a2 += ca*b2f(ra.y&0xffffu); a3 += ca*b2f(ra.y>>16);
        }
        uint2 rs = *(const uint2*)(H2 + (size_t)node * 256 + ci);
        const float sc = dn * dn, cv = cs + sc;
        float f0 = a0 + sc*b2f(rs.x&0xffffu) + cv*vv.x + bb.x;
        float f1 = a1 + sc*b2f(rs.x>>16)     + cv*vv.y + bb.y;
        float f2 = a2 + sc*b2f(rs.y&0xffffu) + cv*vv.z + bb.z;
        float f3 = a3 + sc*b2f(rs.y>>16)     + cv*vv.w + bb.w;
        uint2 o; o.x = packb(f0, f1); o.y = packb(f2, f3);
        *(uint2*)(OutB + (size_t)node * 256 + ci) = o;
        s0 += f0; q0 += f0*f0; s1 += f1; q1 += f1*f1;
        s2 += f2; q2 += f2*f2; s3 += f3; q3 += f3*f3;
    }
    ls[t] = 0.f; ls[256 + t] = 0.f;
    __syncthreads();
    atomicAdd(&ls[ci], s0);   atomicAdd(&ls[ci+1], s1);
    atomicAdd(&ls[ci+2], s2); atomicAdd(&ls[ci+3], s3);
    atomicAdd(&ls[256+ci], q0);   atomicAdd(&ls[256+ci+1], q1);
    atomicAdd(&ls[256+ci+2], q2); atomicAdd(&ls[256+ci+3], q3);
    __syncthreads();
    atomicAdd(&stats[t], ls[t]);
    atomicAdd(&stats[256 + t], ls[256 + t]);
}

// ---------------- BN apply + ReLU + pool (inline BN finalize) ----------------
__global__ __launch_bounds__(256) void k_bnrelu(const u16* __restrict__ OutB,
                                                const float* __restrict__ stats,
                                                const float* __restrict__ g,
                                                const float* __restrict__ bb_,
                                                u16* __restrict__ Hr,
                                                float* __restrict__ pool) {
    __shared__ float lp[256];
    const int t = threadIdx.x;
    const int cg = (t & 31) * 8;
    const int rg = t >> 5;
    const int r0 = blockIdx.x * SB_ROWS + rg;
    const float inv = 1.0f / (float)N_NODES;
    float gg[8], bc[8];
#pragma unroll
    for (int j = 0; j < 8; j++) {
        int c = cg + j;
        float mu = stats[c] * inv;
        float var = stats[256 + c] * inv - mu * mu;
        float rs = rsqrtf(var + EPS);
        gg[j] = g[c] * rs;
        bc[j] = bb_[c] - mu * gg[j];
    }
    float ps[8];
#pragma unroll
    for (int j = 0; j < 8; j++) ps[j] = 0.f;
#pragma unroll 2
    for (int it = 0; it < SB_ROWS / 8; it++) {
        int r = r0 + it * 8;
        uint4 v = *(const uint4*)(OutB + (size_t)r * 256 + cg);
        float f[8]; unpack8(v, f);
#pragma unroll
        for (int j = 0; j < 8; j++) {
            f[j] = fmaxf(f[j] * gg[j] + bc[j], 0.f);
            ps[j] += f[j];
        }
        uint4 o = {packb(f[0], f[1]), packb(f[2], f[3]), packb(f[4], f[5]), packb(f[6], f[7])};
        *(uint4*)(Hr + (size_t)r * 256 + cg) = o;
    }
    lp[t] = 0.f;
    __syncthreads();
#pragma unroll
    for (int j = 0; j < 8; j++) atomicAdd(&lp[cg + j], ps[j]);
    __syncthreads();
    atomicAdd(&pool[t], lp[t]);
}

// ---------------- virtual node update + v2_next = vx_new @ Wnext ----------------
__global__ void k_vx(const float* __restrict__ pool, const float* __restrict__ vx_old,
                     const float* __restrict__ vnW, const float* __restrict__ vnb,
                     const float* __restrict__ lng, const float* __restrict__ lnb,
                     float* __restrict__ vx_new,
                     const float* __restrict__ Wnext, int ncn, int npn,
                     float* __restrict__ v2n) {
    __shared__ float s[256];
    __shared__ float red[256];
    int t = threadIdx.x;
    s[t] = pool[t] + vx_old[t];
    __syncthreads();
    float y = vnb[t];
    for (int k = 0; k < 256; k++) y += s[k] * vnW[k * 256 + t];
    red[t] = y; __syncthreads();
    for (int off = 128; off > 0; off >>= 1) {
        if (t < off) red[t] += red[t + off];
        __syncthreads();
    }
    float mu = red[0] * (1.f / 256.f);
    __syncthreads();
    float d = y - mu;
    red[t] = d * d; __syncthreads();
    for (int off = 128; off > 0; off >>= 1) {
        if (t < off) red[t] += red[t + off];
        __syncthreads();
    }
    float var = red[0] * (1.f / 256.f);
    float v = fmaxf(d * rsqrtf(var + EPS) * lng[t] + lnb[t], 0.f);
    vx_new[t] = v;
    __syncthreads();
    s[t] = v;
    __syncthreads();
    float acc = 0.f;
    if (t < ncn) {
        for (int k = 0; k < 256; k++) acc += s[k] * Wnext[k * ncn + t];
    }
    if (t < npn) v2n[t] = acc;
}

// ---- layer-2 aggregation + (cs+dn^2)*v2 fold + log_softmax ----
__global__ __launch_bounds__(256) void k_agg2(const u16* __restrict__ H2,
                                              const int* __restrict__ row_start,
                                              const int* __restrict__ counts,
                                              const int* __restrict__ csr,
                                              const float* __restrict__ coefv,
                                              const float* __restrict__ dis,
                                              const float* __restrict__ bias,
                                              const float* __restrict__ v2,
                                              float* __restrict__ OutF) {
    const int t = threadIdx.x, wave = t >> 6, lane = t & 63;
    const int half = lane >> 5, hl = lane & 31;
    const bool gact = hl < 24;   // gather lanes (48 padded channels, 2/lane)
    const bool cact = hl < 20;   // real channel pairs (40)
    const int c0 = 2 * hl;
    float bb0 = 0.f, bb1 = 0.f, vv0 = 0.f, vv1 = 0.f;
    if (cact) {
        float2 bv = *(const float2*)(bias + c0); bb0 = bv.x; bb1 = bv.y;
        float2 vvv = *(const float2*)(v2 + c0);  vv0 = vvv.x; vv1 = vvv.y;
    }
    const int nbase = blockIdx.x * 16 + wave * 4;
    for (int i = 0; i < 4; i++) {
        const int node = nbase + i;
        const int beg = row_start[node], cnt = counts[node];
        const float dn = dis[node];
        float a0 = 0.f, a1 = 0.f, cs = 0.f;
        int e = half;
        for (; e + 6 < cnt; e += 8) {
            int ia = csr[beg+e], ib = csr[beg+e+2], ic = csr[beg+e+4], id = csr[beg+e+6];
            float ca = coefv[beg+e], cb = coefv[beg+e+2], cc = coefv[beg+e+4], cd = coefv[beg+e+6];
            u32 ra = 0, rb = 0, rc = 0, rd = 0;
            if (gact) {
                ra = *(const u32*)(H2 + (size_t)ia * COUTP + c0);
                rb = *(const u32*)(H2 + (size_t)ib * COUTP + c0);
                rc = *(const u32*)(H2 + (size_t)ic * COUTP + c0);
                rd = *(const u32*)(H2 + (size_t)id * COUTP + c0);
            }
            cs += ca + cb + cc + cd;
            a0 += ca*b2f(ra&0xffffu) + cb*b2f(rb&0xffffu) + cc*b2f(rc&0xffffu) + cd*b2f(rd&0xffffu);
            a1 += ca*b2f(ra>>16)     + cb*b2f(rb>>16)     + cc*b2f(rc>>16)     + cd*b2f(rd>>16);
        }
        for (; e < cnt; e += 2) {
            int ia = csr[beg+e]; float ca = coefv[beg+e];
            u32 ra = gact ? *(const u32*)(H2 + (size_t)ia * COUTP + c0) : 0u;
            cs += ca;
            a0 += ca*b2f(ra&0xffffu); a1 += ca*b2f(ra>>16);
        }
        a0 += __shfl_xor(a0, 32);
        a1 += __shfl_xor(a1, 32);
        cs += __shfl_xor(cs, 32);
        const float sc = dn * dn;
        u32 rs_ = gact ? *(const u32*)(H2 + (size_t)node * COUTP + c0) : 0u;
        float h0 = a0 + sc*b2f(rs_&0xffffu) + (cs+sc)*vv0 + bb0;
        float h1 = a1 + sc*b2f(rs_>>16)     + (cs+sc)*vv1 + bb1;
        float m = cact ? fmaxf(h0, h1) : -3.0e38f;
#pragma unroll
        for (int off = 16; off > 0; off >>= 1) m = fmaxf(m, __shfl_xor(m, off));
        float ex = cact ? (expf(h0 - m) + expf(h1 - m)) : 0.f;
        float se = ex;
#pragma unroll
        for (int off = 16; off > 0; off >>= 1) se += __shfl_xor(se, off);
        float lg = logf(se);
        if (cact && half == 0) {
            float2 o = {h0 - m - lg, h1 - m - lg};
            *(float2*)(OutF + (size_t)node * COUT + c0) = o;
        }
    }
}

extern "C" void kernel_launch(void* const* d_in, const int* in_sizes, int n_in,
                              void* d_out, int out_size, void* d_ws, size_t ws_size,
                              hipStream_t stream) {
    const float* x   = (const float*)d_in[0];
    const int*   ei  = (const int*)d_in[1];
    const int*   esrc = ei;
    const int*   edst = ei + N_EDGES;
    const float* W0 = (const float*)d_in[2];  const float* b0 = (const float*)d_in[3];
    const float* W1 = (const float*)d_in[4];  const float* b1 = (const float*)d_in[5];
    const float* W2 = (const float*)d_in[6];  const float* b2 = (const float*)d_in[7];
    const float* bg0 = (const float*)d_in[8]; const float* bb0 = (const float*)d_in[9];
    const float* bg1 = (const float*)d_in[10]; const float* bb1 = (const float*)d_in[11];
    const float* vn_emb = (const float*)d_in[12];
    const float* vW0 = (const float*)d_in[13]; const float* vb0 = (const float*)d_in[14];
    const float* lg0 = (const float*)d_in[15]; const float* lb0 = (const float*)d_in[16];
    const float* vW1 = (const float*)d_in[17]; const float* vb1 = (const float*)d_in[18];
    const float* lg1 = (const float*)d_in[19]; const float* lb1 = (const float*)d_in[20];

    char* w = (char*)d_ws;
    auto alloc = [&](size_t bytes) { void* p = (void*)w; w += ((bytes + 255) / 256) * 256; return p; };
    u16* H2    = (u16*)alloc((size_t)N_NODES * 256 * 2);
    u16* HR    = (u16*)alloc((size_t)N_NODES * 256 * 2);
    u16* OutB  = (u16*)alloc((size_t)N_NODES * 256 * 2);
    int* csr   = (int*)alloc((size_t)N_EDGES * 4);
    float* coefv = (float*)alloc((size_t)N_EDGES * 4);
    int* counts = (int*)alloc((size_t)N_NODES * 4);
    int* rowst  = (int*)alloc((size_t)N_NODES * 4);
    int* cursor = (int*)alloc((size_t)N_NODES * 4);
    float* dis  = (float*)alloc((size_t)N_NODES * 4);
    u16* Wtb0 = (u16*)alloc(256 * 256 * 2);
    u16* Wtb1 = (u16*)alloc(256 * 256 * 2);
    u16* Wt2b = (u16*)alloc(COUTP * 256 * 2);
    int* scanblk = (int*)alloc(128 * 4);
    float* stats = (float*)alloc(768 * 4);   // sum[256], sumsq[256], pool[256]
    float* vxA = (float*)alloc(256 * 4);
    float* vxB = (float*)alloc(256 * 4);
    float* v20 = (float*)alloc(256 * 4);
    float* v21 = (float*)alloc(256 * 4);
    float* v22 = (float*)alloc(64 * 4);
    (void)ws_size; (void)in_sizes; (void)n_in; (void)out_size; (void)vxB;

    // ---- graph prep: degrees + CSR + edge coefficients ----
    hipMemsetAsync(counts, 0, (size_t)N_NODES * 4, stream);
    k_count<<<(N_EDGES + 255) / 256, 256, 0, stream>>>(edst, counts);
    k_scan1<<<NSCAN_BLK, 256, 0, stream>>>(counts, rowst, scanblk);
    k_scan2<<<1, 128, 0, stream>>>(scanblk);
    k_scan3<<<(N_NODES + 255) / 256, 256, 0, stream>>>(rowst, scanblk, cursor, counts, dis);
    k_fill<<<(N_EDGES + 255) / 256, 256, 0, stream>>>(esrc, edst, cursor, csr, dis, coefv);

    // ---- weight prep ----
    k_wt3<<<512 + COUTP, 256, 0, stream>>>(W0, W1, W2, Wtb0, Wtb1, Wt2b);
    k_xconv<<<(N_NODES * 256 / 8 + 255) / 256, 256, 0, stream>>>(x, HR);
    k_vecmat<<<1, 256, 0, stream>>>(vn_emb, W0, 256, 256, v20);

    const int aggblk = (N_NODES + 63) / 64;

    // ---- layer 0 ----
    k_gemm<<<(N_NODES + 63) / 64, 256, 0, stream>>>(HR, Wtb0, H2);
    hipMemsetAsync(stats, 0, 768 * 4, stream);
    k_agg<<<aggblk, 256, 0, stream>>>(H2, rowst, counts, csr, coefv, dis, b0, v20, OutB, stats);
    k_bnrelu<<<SB_NBLK, 256, 0, stream>>>(OutB, stats, bg0, bb0, HR, stats + 512);
    k_vx<<<1, 256, 0, stream>>>(stats + 512, vn_emb, vW0, vb0, lg0, lb0, vxA, W1, 256, 256, v21);

    // ---- layer 1 ----
    k_gemm<<<(N_NODES + 63) / 64, 256, 0, stream>>>(HR, Wtb1, H2);
    hipMemsetAsync(stats, 0, 768 * 4, stream);
    k_agg<<<aggblk, 256, 0, stream>>>(H2, rowst, counts, csr, coefv, dis, b1, v21, OutB, stats);
    k_bnrelu<<<SB_NBLK, 256, 0, stream>>>(OutB, stats, bg1, bb1, HR, stats + 512);
    k_vx<<<1, 256, 0, stream>>>(stats + 512, vxA, vW1, vb1, lg1, lb1, vxB, W2, COUT, COUTP, v22);

    // ---- layer 2 + log_softmax ----
    k_gemm2<<<(N_NODES + 63) / 64, 256, 0, stream>>>(HR, Wt2b, H2);
    k_agg2<<<N_NODES / 16, 256, 0, stream>>>(H2, rowst, counts, csr, coefv, dis, b2, v22, (float*)d_out);
}

// Round 6
// 779.112 us; speedup vs baseline: 1.2833x; 1.0087x over previous
//
#include <hip/hip_runtime.h>
#include <hip/hip_bf16.h>
#include <cstdint>

#define N_NODES 100000
#define N_EDGES 800000
#define CH      256
#define COUT    40
#define COUTP   48
#define EPS     1e-5f
#define SCAN_CHUNK 1024
#define NSCAN_BLK  98   // ceil(100000/1024)
#define SB_NBLK 500
#define SB_ROWS 200     // 500*200 = 100000 exactly

typedef unsigned short u16;
typedef unsigned int   u32;
typedef short s16x8 __attribute__((ext_vector_type(8)));
typedef float f32x4 __attribute__((ext_vector_type(4)));

__device__ __forceinline__ float b2f(u32 u) { return __uint_as_float(u << 16); }
__device__ __forceinline__ u16 f2b(float f) {
    u32 u = __float_as_uint(f);
    u32 r = (u + 0x7fffu + ((u >> 16) & 1u)) >> 16;   // RNE
    return (u16)r;
}
__device__ __forceinline__ u32 packb(float a, float b) {
    return (u32)f2b(a) | ((u32)f2b(b) << 16);
}
__device__ __forceinline__ void unpack8(uint4 v, float* f) {
    f[0] = b2f(v.x & 0xffffu); f[1] = b2f(v.x >> 16);
    f[2] = b2f(v.y & 0xffffu); f[3] = b2f(v.y >> 16);
    f[4] = b2f(v.z & 0xffffu); f[5] = b2f(v.z >> 16);
    f[6] = b2f(v.w & 0xffffu); f[7] = b2f(v.w >> 16);
}

// ---------------- CSR build ----------------
__global__ void k_count(const int* __restrict__ dst, int* __restrict__ counts) {
    int e = blockIdx.x * 256 + threadIdx.x;
    if (e < N_EDGES) atomicAdd(&counts[dst[e]], 1);
}

__global__ void k_scan1(const int* __restrict__ counts, int* __restrict__ partial,
                        int* __restrict__ blocksums) {
    __shared__ int sdata[256];
    int base = blockIdx.x * SCAN_CHUNK;
    int t = threadIdx.x;
    int v[4]; int s = 0;
    for (int j = 0; j < 4; j++) {
        int i = base + t * 4 + j;
        v[j] = (i < N_NODES) ? counts[i] : 0;
        s += v[j];
    }
    sdata[t] = s; __syncthreads();
    for (int off = 1; off < 256; off <<= 1) {
        int x = (t >= off) ? sdata[t - off] : 0;
        __syncthreads();
        sdata[t] += x;
        __syncthreads();
    }
    int incl = sdata[t];
    int run = incl - s;
    if (t == 255) blocksums[blockIdx.x] = incl;
    for (int j = 0; j < 4; j++) {
        int i = base + t * 4 + j;
        if (i < N_NODES) partial[i] = run;
        run += v[j];
    }
}

__global__ void k_scan2(int* __restrict__ blocksums) {
    __shared__ int sd[128];
    int t = threadIdx.x;
    int v = (t < NSCAN_BLK) ? blocksums[t] : 0;
    sd[t] = v; __syncthreads();
    for (int off = 1; off < 128; off <<= 1) {
        int x = (t >= off) ? sd[t - off] : 0;
        __syncthreads();
        sd[t] += x;
        __syncthreads();
    }
    if (t < NSCAN_BLK) blocksums[t] = sd[t] - v;
}

__global__ void k_scan3(int* __restrict__ row_start, const int* __restrict__ blocksums,
                        int* __restrict__ cursor, const int* __restrict__ counts,
                        float* __restrict__ dis) {
    int i = blockIdx.x * 256 + threadIdx.x;
    if (i < N_NODES) {
        int v = row_start[i] + blocksums[i >> 10];
        row_start[i] = v;
        cursor[i] = v;
        dis[i] = rsqrtf(1.0f + (float)counts[i]);
    }
}

__global__ void k_fill(const int* __restrict__ src, const int* __restrict__ dst,
                       int* __restrict__ cursor, int* __restrict__ csr,
                       const float* __restrict__ dis, float* __restrict__ coefv) {
    int e = blockIdx.x * 256 + threadIdx.x;
    if (e < N_EDGES) {
        int d = dst[e], s = src[e];
        int p = atomicAdd(&cursor[d], 1);
        csr[p] = s;
        coefv[p] = dis[s] * dis[d];
    }
}

// ---------------- weight transpose (all 3) + bf16 convert ----------------
__global__ void k_wt3(const float* __restrict__ W0, const float* __restrict__ W1,
                      const float* __restrict__ W2,
                      u16* __restrict__ T0, u16* __restrict__ T1, u16* __restrict__ T2) {
    int b = blockIdx.x, k = threadIdx.x;
    if (b < 256) {
        T0[b * 256 + k] = f2b(W0[k * 256 + b]);
    } else if (b < 512) {
        int n = b - 256;
        T1[n * 256 + k] = f2b(W1[k * 256 + n]);
    } else {
        int n = b - 512;
        T2[n * 256 + k] = f2b(n < COUT ? W2[k * COUT + n] : 0.f);
    }
}

// ---------------- tiny: outv[j] = sum_k vec[k] * W[k*ncols+j] ----------------
__global__ void k_vecmat(const float* __restrict__ vec, const float* __restrict__ W,
                         int ncols, int npad, float* __restrict__ outv) {
    __shared__ float s[256];
    int t = threadIdx.x;
    s[t] = vec[t];
    __syncthreads();
    float acc = 0.f;
    if (t < ncols) {
        for (int k = 0; k < 256; k++) acc += s[k] * W[k * ncols + t];
    }
    if (t < npad) outv[t] = acc;
}

// ---------------- GEMM (bf16 A): Hout[N,256] = A[N,256] @ W ----------------
__global__ __launch_bounds__(256) void k_gemm(const u16* __restrict__ A,
                                              const u16* __restrict__ Wt,
                                              u16* __restrict__ Hout) {
    __shared__ u16 Bs[256 * 72];
    __shared__ u16 As[64 * 72];
    const int t = threadIdx.x;
    const int wave = t >> 6, lane = t & 63;
    const int lm = lane & 15, quad = lane >> 4;
    const int m0 = blockIdx.x * 64;
    const int ar = t >> 2, as_ = (t & 3) * 16;
    const int arow = m0 + ar;
    const f32x4 vz = {0.f, 0.f, 0.f, 0.f};
    f32x4 acc[4][4];
    for (int m = 0; m < 4; m++)
        for (int c = 0; c < 4; c++) acc[m][c] = vz;

    for (int k0 = 0; k0 < 256; k0 += 64) {
        {
            const uint4* bsrc = (const uint4*)(Wt + t * 256 + k0);
            uint4* bdst = (uint4*)(Bs + t * 72);
#pragma unroll
            for (int j = 0; j < 8; j++) bdst[j] = bsrc[j];
            uint4 a0v = {0,0,0,0}, a1v = {0,0,0,0};
            if (arow < N_NODES) {
                const uint4* asrc = (const uint4*)(A + (size_t)arow * 256 + k0 + as_);
                a0v = asrc[0]; a1v = asrc[1];
            }
            uint4* adst = (uint4*)(As + ar * 72 + as_);
            adst[0] = a0v; adst[1] = a1v;
        }
        __syncthreads();
#pragma unroll
        for (int kk = 0; kk < 64; kk += 32) {
            s16x8 af[4], bf[4];
#pragma unroll
            for (int m = 0; m < 4; m++)
                af[m] = *(const s16x8*)(As + (m * 16 + lm) * 72 + kk + quad * 8);
#pragma unroll
            for (int c = 0; c < 4; c++)
                bf[c] = *(const s16x8*)(Bs + (wave * 64 + c * 16 + lm) * 72 + kk + quad * 8);
#pragma unroll
            for (int c = 0; c < 4; c++)
#pragma unroll
                for (int m = 0; m < 4; m++)
                    acc[m][c] = __builtin_amdgcn_mfma_f32_16x16x32_bf16(af[m], bf[c], acc[m][c], 0, 0, 0);
        }
        __syncthreads();
    }
#pragma unroll
    for (int m = 0; m < 4; m++) {
#pragma unroll
        for (int c = 0; c < 4; c++) {
            int col = wave * 64 + c * 16 + lm;
#pragma unroll
            for (int i = 0; i < 4; i++) {
                int row = m0 + m * 16 + quad * 4 + i;
                if (row < N_NODES) Hout[(size_t)row * 256 + col] = f2b(acc[m][c][i]);
            }
        }
    }
}

// ---------------- GEMM (fp32 A, layer 0): Hout[N,256] = bf16(x) @ W ----------------
__global__ __launch_bounds__(256) void k_gemm_f32a(const float* __restrict__ A,
                                                   const u16* __restrict__ Wt,
                                                   u16* __restrict__ Hout) {
    __shared__ u16 Bs[256 * 72];
    __shared__ u16 As[64 * 72];
    const int t = threadIdx.x;
    const int wave = t >> 6, lane = t & 63;
    const int lm = lane & 15, quad = lane >> 4;
    const int m0 = blockIdx.x * 64;
    const int ar = t >> 2, as_ = (t & 3) * 16;   // 16 elems (32 B bf16) per thread
    const int arow = m0 + ar;
    const f32x4 vz = {0.f, 0.f, 0.f, 0.f};
    f32x4 acc[4][4];
    for (int m = 0; m < 4; m++)
        for (int c = 0; c < 4; c++) acc[m][c] = vz;

    for (int k0 = 0; k0 < 256; k0 += 64) {
        {
            const uint4* bsrc = (const uint4*)(Wt + t * 256 + k0);
            uint4* bdst = (uint4*)(Bs + t * 72);
#pragma unroll
            for (int j = 0; j < 8; j++) bdst[j] = bsrc[j];
            uint4 p0 = {0,0,0,0}, p1 = {0,0,0,0};
            if (arow < N_NODES) {
                const float4* asrc = (const float4*)(A + (size_t)arow * 256 + k0 + as_);
                float4 x0 = asrc[0], x1 = asrc[1], x2 = asrc[2], x3 = asrc[3];
                p0.x = packb(x0.x, x0.y); p0.y = packb(x0.z, x0.w);
                p0.z = packb(x1.x, x1.y); p0.w = packb(x1.z, x1.w);
                p1.x = packb(x2.x, x2.y); p1.y = packb(x2.z, x2.w);
                p1.z = packb(x3.x, x3.y); p1.w = packb(x3.z, x3.w);
            }
            uint4* adst = (uint4*)(As + ar * 72 + as_);
            adst[0] = p0; adst[1] = p1;
        }
        __syncthreads();
#pragma unroll
        for (int kk = 0; kk < 64; kk += 32) {
            s16x8 af[4], bf[4];
#pragma unroll
            for (int m = 0; m < 4; m++)
                af[m] = *(const s16x8*)(As + (m * 16 + lm) * 72 + kk + quad * 8);
#pragma unroll
            for (int c = 0; c < 4; c++)
                bf[c] = *(const s16x8*)(Bs + (wave * 64 + c * 16 + lm) * 72 + kk + quad * 8);
#pragma unroll
            for (int c = 0; c < 4; c++)
#pragma unroll
                for (int m = 0; m < 4; m++)
                    acc[m][c] = __builtin_amdgcn_mfma_f32_16x16x32_bf16(af[m], bf[c], acc[m][c], 0, 0, 0);
        }
        __syncthreads();
    }
#pragma unroll
    for (int m = 0; m < 4; m++) {
#pragma unroll
        for (int c = 0; c < 4; c++) {
            int col = wave * 64 + c * 16 + lm;
#pragma unroll
            for (int i = 0; i < 4; i++) {
                int row = m0 + m * 16 + quad * 4 + i;
                if (row < N_NODES) Hout[(size_t)row * 256 + col] = f2b(acc[m][c][i]);
            }
        }
    }
}

// ---------------- GEMM layer 2: Hout[N,48] = A[N,256] @ W2pad ----------------
__global__ __launch_bounds__(256) void k_gemm2(const u16* __restrict__ A,
                                               const u16* __restrict__ Wt,
                                               u16* __restrict__ Hout) {
    __shared__ u16 Bs[48 * 72];
    __shared__ u16 As[64 * 72];
    const int t = threadIdx.x;
    const int wave = t >> 6, lane = t & 63;
    const int lm = lane & 15, quad = lane >> 4;
    const int m0 = blockIdx.x * 64;
    const int ar = t >> 2, as_ = (t & 3) * 16;
    const int arow = m0 + ar;
    const f32x4 vz = {0.f, 0.f, 0.f, 0.f};
    f32x4 acc[3]; acc[0] = vz; acc[1] = vz; acc[2] = vz;

    for (int k0 = 0; k0 < 256; k0 += 64) {
        {
            if (t < 48) {
                const uint4* bsrc = (const uint4*)(Wt + t * 256 + k0);
                uint4* bdst = (uint4*)(Bs + t * 72);
#pragma unroll
                for (int j = 0; j < 8; j++) bdst[j] = bsrc[j];
            }
            uint4 a0v = {0,0,0,0}, a1v = {0,0,0,0};
            if (arow < N_NODES) {
                const uint4* asrc = (const uint4*)(A + (size_t)arow * 256 + k0 + as_);
                a0v = asrc[0]; a1v = asrc[1];
            }
            uint4* adst = (uint4*)(As + ar * 72 + as_);
            adst[0] = a0v; adst[1] = a1v;
        }
        __syncthreads();
#pragma unroll
        for (int kk = 0; kk < 64; kk += 32) {
            s16x8 af = *(const s16x8*)(As + (wave * 16 + lm) * 72 + kk + quad * 8);
#pragma unroll
            for (int c = 0; c < 3; c++) {
                s16x8 bf = *(const s16x8*)(Bs + (c * 16 + lm) * 72 + kk + quad * 8);
                acc[c] = __builtin_amdgcn_mfma_f32_16x16x32_bf16(af, bf, acc[c], 0, 0, 0);
            }
        }
        __syncthreads();
    }
#pragma unroll
    for (int c = 0; c < 3; c++) {
        int col = c * 16 + lm;
#pragma unroll
        for (int i = 0; i < 4; i++) {
            int row = m0 + wave * 16 + quad * 4 + i;
            if (row < N_NODES) Hout[(size_t)row * COUTP + col] = f2b(acc[c][i]);
        }
    }
}

// ---- aggregation L0/L1: one node per HALF-WAVE (32 lanes x uint4 = 512 B row) ----
// 2 independent node streams per wave => 8 gathers in flight. 16 nodes/wave, grid = ceil(N/64)
__global__ __launch_bounds__(256) void k_agg(const u16* __restrict__ H2,
                                             const int* __restrict__ row_start,
                                             const int* __restrict__ counts,
                                             const int* __restrict__ csr,
                                             const float* __restrict__ coefv,
                                             const float* __restrict__ dis,
                                             const float* __restrict__ bias,
                                             const float* __restrict__ v2,
                                             u16* __restrict__ OutB,
                                             float* __restrict__ stats) {
    __shared__ float ls[512];
    const int t = threadIdx.x, wave = t >> 6, lane = t & 63;
    const int half = lane >> 5, hl = lane & 31;
    const int ci = hl * 8;   // 8 channels/lane
    float bb[8], vv[8];
    {
        float4 a = *(const float4*)(bias + ci);
        float4 b = *(const float4*)(bias + ci + 4);
        float4 c = *(const float4*)(v2 + ci);
        float4 d = *(const float4*)(v2 + ci + 4);
        bb[0]=a.x; bb[1]=a.y; bb[2]=a.z; bb[3]=a.w; bb[4]=b.x; bb[5]=b.y; bb[6]=b.z; bb[7]=b.w;
        vv[0]=c.x; vv[1]=c.y; vv[2]=c.z; vv[3]=c.w; vv[4]=d.x; vv[5]=d.y; vv[6]=d.z; vv[7]=d.w;
    }
    float s[8], q[8];
#pragma unroll
    for (int j = 0; j < 8; j++) { s[j] = 0.f; q[j] = 0.f; }
    const int nbase = blockIdx.x * 64 + wave * 16 + half;
    for (int i = 0; i < 16; i += 2) {
        const int node = nbase + i;
        if (node >= N_NODES) break;
        const int beg = row_start[node], cnt = counts[node];
        const float dn = dis[node];
        float a[8];
#pragma unroll
        for (int j = 0; j < 8; j++) a[j] = 0.f;
        float cs = 0.f;
        int e = 0;
        for (; e + 4 <= cnt; e += 4) {
            int ia = csr[beg+e], ib = csr[beg+e+1], ic = csr[beg+e+2], id = csr[beg+e+3];
            float ca = coefv[beg+e], cb = coefv[beg+e+1], cc = coefv[beg+e+2], cd = coefv[beg+e+3];
            uint4 ra = *(const uint4*)(H2 + (size_t)ia * 256 + ci);
            uint4 rb = *(const uint4*)(H2 + (size_t)ib * 256 + ci);
            uint4 rc = *(const uint4*)(H2 + (size_t)ic * 256 + ci);
            uint4 rd = *(const uint4*)(H2 + (size_t)id * 256 + ci);
            cs += ca + cb + cc + cd;
            float fa[8], fb[8], fc[8], fd[8];
            unpack8(ra, fa); unpack8(rb, fb); unpack8(rc, fc); unpack8(rd, fd);
#pragma unroll
            for (int j = 0; j < 8; j++)
                a[j] += ca * fa[j] + cb * fb[j] + cc * fc[j] + cd * fd[j];
        }
        for (; e < cnt; e++) {
            int ia = csr[beg+e]; float ca = coefv[beg+e];
            uint4 ra = *(const uint4*)(H2 + (size_t)ia * 256 + ci);
            cs += ca;
            float fa[8]; unpack8(ra, fa);
#pragma unroll
            for (int j = 0; j < 8; j++) a[j] += ca * fa[j];
        }
        uint4 rs = *(const uint4*)(H2 + (size_t)node * 256 + ci);
        float fs[8]; unpack8(rs, fs);
        const float sc = dn * dn, cv = cs + sc;
        float f[8];
#pragma unroll
        for (int j = 0; j < 8; j++) {
            f[j] = a[j] + sc * fs[j] + cv * vv[j] + bb[j];
            s[j] += f[j]; q[j] += f[j] * f[j];
        }
        uint4 o = {packb(f[0], f[1]), packb(f[2], f[3]), packb(f[4], f[5]), packb(f[6], f[7])};
        *(uint4*)(OutB + (size_t)node * 256 + ci) = o;
    }
    ls[t] = 0.f; ls[256 + t] = 0.f;
    __syncthreads();
#pragma unroll
    for (int j = 0; j < 8; j++) {
        atomicAdd(&ls[ci + j], s[j]);
        atomicAdd(&ls[256 + ci + j], q[j]);
    }
    __syncthreads();
    atomicAdd(&stats[t], ls[t]);
    atomicAdd(&stats[256 + t], ls[256 + t]);
}

// ---------------- BN apply + ReLU + pool (inline BN finalize) ----------------
__global__ __launch_bounds__(256) void k_bnrelu(const u16* __restrict__ OutB,
                                                const float* __restrict__ stats,
                                                const float* __restrict__ g,
                                                const float* __restrict__ bb_,
                                                u16* __restrict__ Hr,
                                                float* __restrict__ pool) {
    __shared__ float lp[256];
    const int t = threadIdx.x;
    const int cg = (t & 31) * 8;
    const int rg = t >> 5;
    const int r0 = blockIdx.x * SB_ROWS + rg;
    const float inv = 1.0f / (float)N_NODES;
    float gg[8], bc[8];
#pragma unroll
    for (int j = 0; j < 8; j++) {
        int c = cg + j;
        float mu = stats[c] * inv;
        float var = stats[256 + c] * inv - mu * mu;
        float rs = rsqrtf(var + EPS);
        gg[j] = g[c] * rs;
        bc[j] = bb_[c] - mu * gg[j];
    }
    float ps[8];
#pragma unroll
    for (int j = 0; j < 8; j++) ps[j] = 0.f;
#pragma unroll 2
    for (int it = 0; it < SB_ROWS / 8; it++) {
        int r = r0 + it * 8;
        uint4 v = *(const uint4*)(OutB + (size_t)r * 256 + cg);
        float f[8]; unpack8(v, f);
#pragma unroll
        for (int j = 0; j < 8; j++) {
            f[j] = fmaxf(f[j] * gg[j] + bc[j], 0.f);
            ps[j] += f[j];
        }
        uint4 o = {packb(f[0], f[1]), packb(f[2], f[3]), packb(f[4], f[5]), packb(f[6], f[7])};
        *(uint4*)(Hr + (size_t)r * 256 + cg) = o;
    }
    lp[t] = 0.f;
    __syncthreads();
#pragma unroll
    for (int j = 0; j < 8; j++) atomicAdd(&lp[cg + j], ps[j]);
    __syncthreads();
    atomicAdd(&pool[t], lp[t]);
}

// ---------------- virtual node update + v2_next = vx_new @ Wnext ----------------
__global__ void k_vx(const float* __restrict__ pool, const float* __restrict__ vx_old,
                     const float* __restrict__ vnW, const float* __restrict__ vnb,
                     const float* __restrict__ lng, const float* __restrict__ lnb,
                     float* __restrict__ vx_new,
                     const float* __restrict__ Wnext, int ncn, int npn,
                     float* __restrict__ v2n) {
    __shared__ float s[256];
    __shared__ float red[256];
    int t = threadIdx.x;
    s[t] = pool[t] + vx_old[t];
    __syncthreads();
    float y = vnb[t];
    for (int k = 0; k < 256; k++) y += s[k] * vnW[k * 256 + t];
    red[t] = y; __syncthreads();
    for (int off = 128; off > 0; off >>= 1) {
        if (t < off) red[t] += red[t + off];
        __syncthreads();
    }
    float mu = red[0] * (1.f / 256.f);
    __syncthreads();
    float d = y - mu;
    red[t] = d * d; __syncthreads();
    for (int off = 128; off > 0; off >>= 1) {
        if (t < off) red[t] += red[t + off];
        __syncthreads();
    }
    float var = red[0] * (1.f / 256.f);
    float v = fmaxf(d * rsqrtf(var + EPS) * lng[t] + lnb[t], 0.f);
    vx_new[t] = v;
    __syncthreads();
    s[t] = v;
    __syncthreads();
    float acc = 0.f;
    if (t < ncn) {
        for (int k = 0; k < 256; k++) acc += s[k] * Wnext[k * ncn + t];
    }
    if (t < npn) v2n[t] = acc;
}

// ---- layer-2 aggregation + (cs+dn^2)*v2 fold + log_softmax ----
__global__ __launch_bounds__(256) void k_agg2(const u16* __restrict__ H2,
                                              const int* __restrict__ row_start,
                                              const int* __restrict__ counts,
                                              const int* __restrict__ csr,
                                              const float* __restrict__ coefv,
                                              const float* __restrict__ dis,
                                              const float* __restrict__ bias,
                                              const float* __restrict__ v2,
                                              float* __restrict__ OutF) {
    const int t = threadIdx.x, wave = t >> 6, lane = t & 63;
    const int half = lane >> 5, hl = lane & 31;
    const bool gact = hl < 24;
    const bool cact = hl < 20;
    const int c0 = 2 * hl;
    float bb0 = 0.f, bb1 = 0.f, vv0 = 0.f, vv1 = 0.f;
    if (cact) {
        float2 bv = *(const float2*)(bias + c0); bb0 = bv.x; bb1 = bv.y;
        float2 vvv = *(const float2*)(v2 + c0);  vv0 = vvv.x; vv1 = vvv.y;
    }
    const int nbase = blockIdx.x * 16 + wave * 4;
    for (int i = 0; i < 4; i++) {
        const int node = nbase + i;
        const int beg = row_start[node], cnt = counts[node];
        const float dn = dis[node];
        float a0 = 0.f, a1 = 0.f, cs = 0.f;
        int e = half;
        for (; e + 6 < cnt; e += 8) {
            int ia = csr[beg+e], ib = csr[beg+e+2], ic = csr[beg+e+4], id = csr[beg+e+6];
            float ca = coefv[beg+e], cb = coefv[beg+e+2], cc = coefv[beg+e+4], cd = coefv[beg+e+6];
            u32 ra = 0, rb = 0, rc = 0, rd = 0;
            if (gact) {
                ra = *(const u32*)(H2 + (size_t)ia * COUTP + c0);
                rb = *(const u32*)(H2 + (size_t)ib * COUTP + c0);
                rc = *(const u32*)(H2 + (size_t)ic * COUTP + c0);
                rd = *(const u32*)(H2 + (size_t)id * COUTP + c0);
            }
            cs += ca + cb + cc + cd;
            a0 += ca*b2f(ra&0xffffu) + cb*b2f(rb&0xffffu) + cc*b2f(rc&0xffffu) + cd*b2f(rd&0xffffu);
            a1 += ca*b2f(ra>>16)     + cb*b2f(rb>>16)     + cc*b2f(rc>>16)     + cd*b2f(rd>>16);
        }
        for (; e < cnt; e += 2) {
            int ia = csr[beg+e]; float ca = coefv[beg+e];
            u32 ra = gact ? *(const u32*)(H2 + (size_t)ia * COUTP + c0) : 0u;
            cs += ca;
            a0 += ca*b2f(ra&0xffffu); a1 += ca*b2f(ra>>16);
        }
        a0 += __shfl_xor(a0, 32);
        a1 += __shfl_xor(a1, 32);
        cs += __shfl_xor(cs, 32);
        const float sc = dn * dn;
        u32 rs_ = gact ? *(const u32*)(H2 + (size_t)node * COUTP + c0) : 0u;
        float h0 = a0 + sc*b2f(rs_&0xffffu) + (cs+sc)*vv0 + bb0;
        float h1 = a1 + sc*b2f(rs_>>16)     + (cs+sc)*vv1 + bb1;
        float m = cact ? fmaxf(h0, h1) : -3.0e38f;
#pragma unroll
        for (int off = 16; off > 0; off >>= 1) m = fmaxf(m, __shfl_xor(m, off));
        float ex = cact ? (expf(h0 - m) + expf(h1 - m)) : 0.f;
        float se = ex;
#pragma unroll
        for (int off = 16; off > 0; off >>= 1) se += __shfl_xor(se, off);
        float lg = logf(se);
        if (cact && half == 0) {
            float2 o = {h0 - m - lg, h1 - m - lg};
            *(float2*)(OutF + (size_t)node * COUT + c0) = o;
        }
    }
}

extern "C" void kernel_launch(void* const* d_in, const int* in_sizes, int n_in,
                              void* d_out, int out_size, void* d_ws, size_t ws_size,
                              hipStream_t stream) {
    const float* x   = (const float*)d_in[0];
    const int*   ei  = (const int*)d_in[1];
    const int*   esrc = ei;
    const int*   edst = ei + N_EDGES;
    const float* W0 = (const float*)d_in[2];  const float* b0 = (const float*)d_in[3];
    const float* W1 = (const float*)d_in[4];  const float* b1 = (const float*)d_in[5];
    const float* W2 = (const float*)d_in[6];  const float* b2 = (const float*)d_in[7];
    const float* bg0 = (const float*)d_in[8]; const float* bb0 = (const float*)d_in[9];
    const float* bg1 = (const float*)d_in[10]; const float* bb1 = (const float*)d_in[11];
    const float* vn_emb = (const float*)d_in[12];
    const float* vW0 = (const float*)d_in[13]; const float* vb0 = (const float*)d_in[14];
    const float* lg0 = (const float*)d_in[15]; const float* lb0 = (const float*)d_in[16];
    const float* vW1 = (const float*)d_in[17]; const float* vb1 = (const float*)d_in[18];
    const float* lg1 = (const float*)d_in[19]; const float* lb1 = (const float*)d_in[20];

    char* w = (char*)d_ws;
    auto alloc = [&](size_t bytes) { void* p = (void*)w; w += ((bytes + 255) / 256) * 256; return p; };
    u16* H2    = (u16*)alloc((size_t)N_NODES * 256 * 2);
    u16* HR    = (u16*)alloc((size_t)N_NODES * 256 * 2);
    u16* OutB  = (u16*)alloc((size_t)N_NODES * 256 * 2);
    int* csr   = (int*)alloc((size_t)N_EDGES * 4);
    float* coefv = (float*)alloc((size_t)N_EDGES * 4);
    int* counts = (int*)alloc((size_t)N_NODES * 4);
    int* rowst  = (int*)alloc((size_t)N_NODES * 4);
    int* cursor = (int*)alloc((size_t)N_NODES * 4);
    float* dis  = (float*)alloc((size_t)N_NODES * 4);
    u16* Wtb0 = (u16*)alloc(256 * 256 * 2);
    u16* Wtb1 = (u16*)alloc(256 * 256 * 2);
    u16* Wt2b = (u16*)alloc(COUTP * 256 * 2);
    int* scanblk = (int*)alloc(128 * 4);
    float* stats = (float*)alloc(768 * 4);   // sum[256], sumsq[256], pool[256]
    float* vxA = (float*)alloc(256 * 4);
    float* vxB = (float*)alloc(256 * 4);
    float* v20 = (float*)alloc(256 * 4);
    float* v21 = (float*)alloc(256 * 4);
    float* v22 = (float*)alloc(64 * 4);
    (void)ws_size; (void)in_sizes; (void)n_in; (void)out_size; (void)vxB;

    // ---- graph prep: degrees + CSR + edge coefficients ----
    hipMemsetAsync(counts, 0, (size_t)N_NODES * 4, stream);
    k_count<<<(N_EDGES + 255) / 256, 256, 0, stream>>>(edst, counts);
    k_scan1<<<NSCAN_BLK, 256, 0, stream>>>(counts, rowst, scanblk);
    k_scan2<<<1, 128, 0, stream>>>(scanblk);
    k_scan3<<<(N_NODES + 255) / 256, 256, 0, stream>>>(rowst, scanblk, cursor, counts, dis);
    k_fill<<<(N_EDGES + 255) / 256, 256, 0, stream>>>(esrc, edst, cursor, csr, dis, coefv);

    // ---- weight prep ----
    k_wt3<<<512 + COUTP, 256, 0, stream>>>(W0, W1, W2, Wtb0, Wtb1, Wt2b);
    k_vecmat<<<1, 256, 0, stream>>>(vn_emb, W0, 256, 256, v20);

    const int aggblk = (N_NODES + 63) / 64;

    // ---- layer 0 ----
    k_gemm_f32a<<<(N_NODES + 63) / 64, 256, 0, stream>>>(x, Wtb0, H2);
    hipMemsetAsync(stats, 0, 768 * 4, stream);
    k_agg<<<aggblk, 256, 0, stream>>>(H2, rowst, counts, csr, coefv, dis, b0, v20, OutB, stats);
    k_bnrelu<<<SB_NBLK, 256, 0, stream>>>(OutB, stats, bg0, bb0, HR, stats + 512);
    k_vx<<<1, 256, 0, stream>>>(stats + 512, vn_emb, vW0, vb0, lg0, lb0, vxA, W1, 256, 256, v21);

    // ---- layer 1 ----
    k_gemm<<<(N_NODES + 63) / 64, 256, 0, stream>>>(HR, Wtb1, H2);
    hipMemsetAsync(stats, 0, 768 * 4, stream);
    k_agg<<<aggblk, 256, 0, stream>>>(H2, rowst, counts, csr, coefv, dis, b1, v21, OutB, stats);
    k_bnrelu<<<SB_NBLK, 256, 0, stream>>>(OutB, stats, bg1, bb1, HR, stats + 512);
    k_vx<<<1, 256, 0, stream>>>(stats + 512, vxA, vW1, vb1, lg1, lb1, vxB, W2, COUT, COUTP, v22);

    // ---- layer 2 + log_softmax ----
    k_gemm2<<<(N_NODES + 63) / 64, 256, 0, stream>>>(HR, Wt2b, H2);
    k_agg2<<<N_NODES / 16, 256, 0, stream>>>(H2, rowst, counts, csr, coefv, dis, b2, v22, (float*)d_out);
}

// Round 7
// 753.193 us; speedup vs baseline: 1.3274x; 1.0344x over previous
//
#include <hip/hip_runtime.h>
#include <hip/hip_bf16.h>
#include <cstdint>

#define N_NODES 100000
#define N_EDGES 800000
#define CH      256
#define COUT    40
#define COUTP   48
#define EPS     1e-5f
#define SCAN_CHUNK 1024
#define NSCAN_BLK  98   // ceil(100000/1024)
#define AGG_NPW 16      // nodes per wave in k_agg

typedef unsigned short u16;
typedef unsigned int   u32;
typedef short s16x8 __attribute__((ext_vector_type(8)));
typedef float f32x4 __attribute__((ext_vector_type(4)));

__device__ __forceinline__ float b2f(u32 u) { return __uint_as_float(u << 16); }
__device__ __forceinline__ u16 f2b(float f) {
    u32 u = __float_as_uint(f);
    u32 r = (u + 0x7fffu + ((u >> 16) & 1u)) >> 16;   // RNE
    return (u16)r;
}
__device__ __forceinline__ u32 packb(float a, float b) {
    return (u32)f2b(a) | ((u32)f2b(b) << 16);
}
__device__ __forceinline__ void unpack8(uint4 v, float* f) {
    f[0] = b2f(v.x & 0xffffu); f[1] = b2f(v.x >> 16);
    f[2] = b2f(v.y & 0xffffu); f[3] = b2f(v.y >> 16);
    f[4] = b2f(v.z & 0xffffu); f[5] = b2f(v.z >> 16);
    f[6] = b2f(v.w & 0xffffu); f[7] = b2f(v.w >> 16);
}

// ---------------- CSR build ----------------
__global__ void k_count(const int* __restrict__ dst, int* __restrict__ counts) {
    int e = blockIdx.x * 256 + threadIdx.x;
    if (e < N_EDGES) atomicAdd(&counts[dst[e]], 1);
}

__global__ void k_scan1(const int* __restrict__ counts, int* __restrict__ partial,
                        int* __restrict__ blocksums) {
    __shared__ int sdata[256];
    int base = blockIdx.x * SCAN_CHUNK;
    int t = threadIdx.x;
    int v[4]; int s = 0;
    for (int j = 0; j < 4; j++) {
        int i = base + t * 4 + j;
        v[j] = (i < N_NODES) ? counts[i] : 0;
        s += v[j];
    }
    sdata[t] = s; __syncthreads();
    for (int off = 1; off < 256; off <<= 1) {
        int x = (t >= off) ? sdata[t - off] : 0;
        __syncthreads();
        sdata[t] += x;
        __syncthreads();
    }
    int incl = sdata[t];
    int run = incl - s;
    if (t == 255) blocksums[blockIdx.x] = incl;
    for (int j = 0; j < 4; j++) {
        int i = base + t * 4 + j;
        if (i < N_NODES) partial[i] = run;
        run += v[j];
    }
}

__global__ void k_scan2(int* __restrict__ blocksums) {
    __shared__ int sd[128];
    int t = threadIdx.x;
    int v = (t < NSCAN_BLK) ? blocksums[t] : 0;
    sd[t] = v; __syncthreads();
    for (int off = 1; off < 128; off <<= 1) {
        int x = (t >= off) ? sd[t - off] : 0;
        __syncthreads();
        sd[t] += x;
        __syncthreads();
    }
    if (t < NSCAN_BLK) blocksums[t] = sd[t] - v;
}

__global__ void k_scan3(int* __restrict__ row_start, const int* __restrict__ blocksums,
                        int* __restrict__ cursor, const int* __restrict__ counts,
                        float* __restrict__ dis) {
    int i = blockIdx.x * 256 + threadIdx.x;
    if (i < N_NODES) {
        int v = row_start[i] + blocksums[i >> 10];
        row_start[i] = v;
        cursor[i] = v;
        dis[i] = rsqrtf(1.0f + (float)counts[i]);
    }
}

// fill packed edge data: {src, coef_bits} — single 8-B store
__global__ void k_fill(const int* __restrict__ src, const int* __restrict__ dst,
                       int* __restrict__ cursor, int2* __restrict__ edata,
                       const float* __restrict__ dis) {
    int e = blockIdx.x * 256 + threadIdx.x;
    if (e < N_EDGES) {
        int d = dst[e], s = src[e];
        int p = atomicAdd(&cursor[d], 1);
        int2 v; v.x = s; v.y = __float_as_int(dis[s] * dis[d]);
        edata[p] = v;
    }
}

// ---------------- weight transpose (all 3) + bf16 convert ----------------
__global__ void k_wt3(const float* __restrict__ W0, const float* __restrict__ W1,
                      const float* __restrict__ W2,
                      u16* __restrict__ T0, u16* __restrict__ T1, u16* __restrict__ T2) {
    int b = blockIdx.x, k = threadIdx.x;
    if (b < 256) {
        T0[b * 256 + k] = f2b(W0[k * 256 + b]);
    } else if (b < 512) {
        int n = b - 256;
        T1[n * 256 + k] = f2b(W1[k * 256 + n]);
    } else {
        int n = b - 512;
        T2[n * 256 + k] = f2b(n < COUT ? W2[k * COUT + n] : 0.f);
    }
}

// ---------------- tiny: outv[j] = sum_k vec[k] * W[k*ncols+j] ----------------
__global__ void k_vecmat(const float* __restrict__ vec, const float* __restrict__ W,
                         int ncols, int npad, float* __restrict__ outv) {
    __shared__ float s[256];
    int t = threadIdx.x;
    s[t] = vec[t];
    __syncthreads();
    float acc = 0.f;
    if (t < ncols) {
        for (int k = 0; k < 256; k++) acc += s[k] * W[k * ncols + t];
    }
    if (t < npad) outv[t] = acc;
}

// ---------------- GEMM (fp32 A, layer 0): Hout[N,256] = bf16(x) @ W ----------------
__global__ __launch_bounds__(256) void k_gemm_f32a(const float* __restrict__ A,
                                                   const u16* __restrict__ Wt,
                                                   u16* __restrict__ Hout) {
    __shared__ u16 Bs[256 * 72];
    __shared__ u16 As[64 * 72];
    const int t = threadIdx.x;
    const int wave = t >> 6, lane = t & 63;
    const int lm = lane & 15, quad = lane >> 4;
    const int m0 = blockIdx.x * 64;
    const int ar = t >> 2, as_ = (t & 3) * 16;
    const int arow = m0 + ar;
    const f32x4 vz = {0.f, 0.f, 0.f, 0.f};
    f32x4 acc[4][4];
    for (int m = 0; m < 4; m++)
        for (int c = 0; c < 4; c++) acc[m][c] = vz;

    for (int k0 = 0; k0 < 256; k0 += 64) {
        {
            const uint4* bsrc = (const uint4*)(Wt + t * 256 + k0);
            uint4* bdst = (uint4*)(Bs + t * 72);
#pragma unroll
            for (int j = 0; j < 8; j++) bdst[j] = bsrc[j];
            uint4 p0 = {0,0,0,0}, p1 = {0,0,0,0};
            if (arow < N_NODES) {
                const float4* asrc = (const float4*)(A + (size_t)arow * 256 + k0 + as_);
                float4 x0 = asrc[0], x1 = asrc[1], x2 = asrc[2], x3 = asrc[3];
                p0.x = packb(x0.x, x0.y); p0.y = packb(x0.z, x0.w);
                p0.z = packb(x1.x, x1.y); p0.w = packb(x1.z, x1.w);
                p1.x = packb(x2.x, x2.y); p1.y = packb(x2.z, x2.w);
                p1.z = packb(x3.x, x3.y); p1.w = packb(x3.z, x3.w);
            }
            uint4* adst = (uint4*)(As + ar * 72 + as_);
            adst[0] = p0; adst[1] = p1;
        }
        __syncthreads();
#pragma unroll
        for (int kk = 0; kk < 64; kk += 32) {
            s16x8 af[4], bf[4];
#pragma unroll
            for (int m = 0; m < 4; m++)
                af[m] = *(const s16x8*)(As + (m * 16 + lm) * 72 + kk + quad * 8);
#pragma unroll
            for (int c = 0; c < 4; c++)
                bf[c] = *(const s16x8*)(Bs + (wave * 64 + c * 16 + lm) * 72 + kk + quad * 8);
#pragma unroll
            for (int c = 0; c < 4; c++)
#pragma unroll
                for (int m = 0; m < 4; m++)
                    acc[m][c] = __builtin_amdgcn_mfma_f32_16x16x32_bf16(af[m], bf[c], acc[m][c], 0, 0, 0);
        }
        __syncthreads();
    }
#pragma unroll
    for (int m = 0; m < 4; m++) {
#pragma unroll
        for (int c = 0; c < 4; c++) {
            int col = wave * 64 + c * 16 + lm;
#pragma unroll
            for (int i = 0; i < 4; i++) {
                int row = m0 + m * 16 + quad * 4 + i;
                if (row < N_NODES) Hout[(size_t)row * 256 + col] = f2b(acc[m][c][i]);
            }
        }
    }
}

// ---- GEMM with fused BN+ReLU on A + pool: Hout = relu(bn(A)) @ W; pool += colsum ----
__global__ __launch_bounds__(256) void k_gemm_bn(const u16* __restrict__ A,
                                                 const float* __restrict__ stats,
                                                 const float* __restrict__ g,
                                                 const float* __restrict__ bv,
                                                 const u16* __restrict__ Wt,
                                                 u16* __restrict__ Hout,
                                                 float* __restrict__ pool) {
    __shared__ u16 Bs[256 * 72];
    __shared__ u16 As[64 * 72];
    __shared__ float ggs[256], bcs[256], pls[256];
    const int t = threadIdx.x;
    const int wave = t >> 6, lane = t & 63;
    const int lm = lane & 15, quad = lane >> 4;
    const int m0 = blockIdx.x * 64;
    const int ar = t >> 2, as_ = (t & 3) * 16;
    const int arow = m0 + ar;
    {
        const float inv = 1.0f / (float)N_NODES;
        float mu = stats[t] * inv;
        float var = stats[256 + t] * inv - mu * mu;
        float rs = rsqrtf(var + EPS);
        float gg = g[t] * rs;
        ggs[t] = gg; bcs[t] = bv[t] - mu * gg;
        pls[t] = 0.f;
    }
    __syncthreads();
    const f32x4 vz = {0.f, 0.f, 0.f, 0.f};
    f32x4 acc[4][4];
    for (int m = 0; m < 4; m++)
        for (int c = 0; c < 4; c++) acc[m][c] = vz;

    for (int k0 = 0; k0 < 256; k0 += 64) {
        {
            const uint4* bsrc = (const uint4*)(Wt + t * 256 + k0);
            uint4* bdst = (uint4*)(Bs + t * 72);
#pragma unroll
            for (int j = 0; j < 8; j++) bdst[j] = bsrc[j];
            float f[16];
            if (arow < N_NODES) {
                const uint4* asrc = (const uint4*)(A + (size_t)arow * 256 + k0 + as_);
                uint4 r0 = asrc[0], r1 = asrc[1];
                unpack8(r0, f); unpack8(r1, f + 8);
#pragma unroll
                for (int j = 0; j < 16; j++) {
                    int c = k0 + as_ + j;
                    f[j] = fmaxf(f[j] * ggs[c] + bcs[c], 0.f);
                }
            } else {
#pragma unroll
                for (int j = 0; j < 16; j++) f[j] = 0.f;
            }
            // pool: reduce over lanes with same (lane&3), add to LDS
#pragma unroll
            for (int j = 0; j < 16; j++) {
                float v = f[j];
                v += __shfl_xor(v, 4);  v += __shfl_xor(v, 8);
                v += __shfl_xor(v, 16); v += __shfl_xor(v, 32);
                if (lane < 4) atomicAdd(&pls[k0 + lane * 16 + j], v);
            }
            uint4 p0, p1;
            p0.x = packb(f[0], f[1]);   p0.y = packb(f[2], f[3]);
            p0.z = packb(f[4], f[5]);   p0.w = packb(f[6], f[7]);
            p1.x = packb(f[8], f[9]);   p1.y = packb(f[10], f[11]);
            p1.z = packb(f[12], f[13]); p1.w = packb(f[14], f[15]);
            uint4* adst = (uint4*)(As + ar * 72 + as_);
            adst[0] = p0; adst[1] = p1;
        }
        __syncthreads();
#pragma unroll
        for (int kk = 0; kk < 64; kk += 32) {
            s16x8 af[4], bf[4];
#pragma unroll
            for (int m = 0; m < 4; m++)
                af[m] = *(const s16x8*)(As + (m * 16 + lm) * 72 + kk + quad * 8);
#pragma unroll
            for (int c = 0; c < 4; c++)
                bf[c] = *(const s16x8*)(Bs + (wave * 64 + c * 16 + lm) * 72 + kk + quad * 8);
#pragma unroll
            for (int c = 0; c < 4; c++)
#pragma unroll
                for (int m = 0; m < 4; m++)
                    acc[m][c] = __builtin_amdgcn_mfma_f32_16x16x32_bf16(af[m], bf[c], acc[m][c], 0, 0, 0);
        }
        __syncthreads();
    }
    // flush pool partials, spread over 8 copies to cut atomic contention
    atomicAdd(&pool[(blockIdx.x & 7) * 256 + t], pls[t]);
#pragma unroll
    for (int m = 0; m < 4; m++) {
#pragma unroll
        for (int c = 0; c < 4; c++) {
            int col = wave * 64 + c * 16 + lm;
#pragma unroll
            for (int i = 0; i < 4; i++) {
                int row = m0 + m * 16 + quad * 4 + i;
                if (row < N_NODES) Hout[(size_t)row * 256 + col] = f2b(acc[m][c][i]);
            }
        }
    }
}

// ---- GEMM layer 2 with fused BN+ReLU + pool: Hout[N,48] = relu(bn(A)) @ W2pad ----
__global__ __launch_bounds__(256) void k_gemm2_bn(const u16* __restrict__ A,
                                                  const float* __restrict__ stats,
                                                  const float* __restrict__ g,
                                                  const float* __restrict__ bv,
                                                  const u16* __restrict__ Wt,
                                                  u16* __restrict__ Hout,
                                                  float* __restrict__ pool) {
    __shared__ u16 Bs[48 * 72];
    __shared__ u16 As[64 * 72];
    __shared__ float ggs[256], bcs[256], pls[256];
    const int t = threadIdx.x;
    const int wave = t >> 6, lane = t & 63;
    const int lm = lane & 15, quad = lane >> 4;
    const int m0 = blockIdx.x * 64;
    const int ar = t >> 2, as_ = (t & 3) * 16;
    const int arow = m0 + ar;
    {
        const float inv = 1.0f / (float)N_NODES;
        float mu = stats[t] * inv;
        float var = stats[256 + t] * inv - mu * mu;
        float rs = rsqrtf(var + EPS);
        float gg = g[t] * rs;
        ggs[t] = gg; bcs[t] = bv[t] - mu * gg;
        pls[t] = 0.f;
    }
    __syncthreads();
    const f32x4 vz = {0.f, 0.f, 0.f, 0.f};
    f32x4 acc[3]; acc[0] = vz; acc[1] = vz; acc[2] = vz;

    for (int k0 = 0; k0 < 256; k0 += 64) {
        {
            if (t < 48) {
                const uint4* bsrc = (const uint4*)(Wt + t * 256 + k0);
                uint4* bdst = (uint4*)(Bs + t * 72);
#pragma unroll
                for (int j = 0; j < 8; j++) bdst[j] = bsrc[j];
            }
            float f[16];
            if (arow < N_NODES) {
                const uint4* asrc = (const uint4*)(A + (size_t)arow * 256 + k0 + as_);
                uint4 r0 = asrc[0], r1 = asrc[1];
                unpack8(r0, f); unpack8(r1, f + 8);
#pragma unroll
                for (int j = 0; j < 16; j++) {
                    int c = k0 + as_ + j;
                    f[j] = fmaxf(f[j] * ggs[c] + bcs[c], 0.f);
                }
            } else {
#pragma unroll
                for (int j = 0; j < 16; j++) f[j] = 0.f;
            }
#pragma unroll
            for (int j = 0; j < 16; j++) {
                float v = f[j];
                v += __shfl_xor(v, 4);  v += __shfl_xor(v, 8);
                v += __shfl_xor(v, 16); v += __shfl_xor(v, 32);
                if (lane < 4) atomicAdd(&pls[k0 + lane * 16 + j], v);
            }
            uint4 p0, p1;
            p0.x = packb(f[0], f[1]);   p0.y = packb(f[2], f[3]);
            p0.z = packb(f[4], f[5]);   p0.w = packb(f[6], f[7]);
            p1.x = packb(f[8], f[9]);   p1.y = packb(f[10], f[11]);
            p1.z = packb(f[12], f[13]); p1.w = packb(f[14], f[15]);
            uint4* adst = (uint4*)(As + ar * 72 + as_);
            adst[0] = p0; adst[1] = p1;
        }
        __syncthreads();
#pragma unroll
        for (int kk = 0; kk < 64; kk += 32) {
            s16x8 af = *(const s16x8*)(As + (wave * 16 + lm) * 72 + kk + quad * 8);
#pragma unroll
            for (int c = 0; c < 3; c++) {
                s16x8 bf = *(const s16x8*)(Bs + (c * 16 + lm) * 72 + kk + quad * 8);
                acc[c] = __builtin_amdgcn_mfma_f32_16x16x32_bf16(af, bf, acc[c], 0, 0, 0);
            }
        }
        __syncthreads();
    }
    atomicAdd(&pool[(blockIdx.x & 7) * 256 + t], pls[t]);
#pragma unroll
    for (int c = 0; c < 3; c++) {
        int col = c * 16 + lm;
#pragma unroll
        for (int i = 0; i < 4; i++) {
            int row = m0 + wave * 16 + quad * 4 + i;
            if (row < N_NODES) Hout[(size_t)row * COUTP + col] = f2b(acc[c][i]);
        }
    }
}

// ---- aggregation L0/L1 (round-3 structure, packed edata): v2 fold + BN stats ----
__global__ __launch_bounds__(256) void k_agg(const u16* __restrict__ H2,
                                             const int* __restrict__ row_start,
                                             const int* __restrict__ counts,
                                             const int2* __restrict__ edata,
                                             const float* __restrict__ dis,
                                             const float* __restrict__ bias,
                                             const float* __restrict__ v2,
                                             u16* __restrict__ OutB,
                                             float* __restrict__ stats) {
    __shared__ float ls[512];
    const int t = threadIdx.x, wave = t >> 6, lane = t & 63, ci = lane * 4;
    const float4 bb = *(const float4*)(bias + ci);
    const float4 vv = *(const float4*)(v2 + ci);
    float s0=0,s1=0,s2=0,s3=0,q0=0,q1=0,q2=0,q3=0;
    const int nbase = blockIdx.x * (4 * AGG_NPW) + wave * AGG_NPW;
    for (int i = 0; i < AGG_NPW; i++) {
        const int node = nbase + i;
        if (node >= N_NODES) break;
        const int beg = row_start[node], cnt = counts[node];
        const float dn = dis[node];
        float a0=0,a1=0,a2=0,a3=0, cs=0;
        int e = 0;
        for (; e + 4 <= cnt; e += 4) {
            int2 ea = edata[beg+e],   eb = edata[beg+e+1];
            int2 ec = edata[beg+e+2], ed = edata[beg+e+3];
            float ca = __int_as_float(ea.y), cb = __int_as_float(eb.y);
            float cc = __int_as_float(ec.y), cd = __int_as_float(ed.y);
            uint2 ra = *(const uint2*)(H2 + (size_t)ea.x * 256 + ci);
            uint2 rb = *(const uint2*)(H2 + (size_t)eb.x * 256 + ci);
            uint2 rc = *(const uint2*)(H2 + (size_t)ec.x * 256 + ci);
            uint2 rd = *(const uint2*)(H2 + (size_t)ed.x * 256 + ci);
            cs += ca + cb + cc + cd;
            a0 += ca*b2f(ra.x&0xffffu) + cb*b2f(rb.x&0xffffu) + cc*b2f(rc.x&0xffffu) + cd*b2f(rd.x&0xffffu);
            a1 += ca*b2f(ra.x>>16)     + cb*b2f(rb.x>>16)     + cc*b2f(rc.x>>16)     + cd*b2f(rd.x>>16);
            a2 += ca*b2f(ra.y&0xffffu) + cb*b2f(rb.y&0xffffu) + cc*b2f(rc.y&0xffffu) + cd*b2f(rd.y&0xffffu);
            a3 += ca*b2f(ra.y>>16)     + cb*b2f(rb.y>>16)     + cc*b2f(rc.y>>16)     + cd*b2f(rd.y>>16);
        }
        for (; e < cnt; e++) {
            int2 ea = edata[beg+e];
            float ca = __int_as_float(ea.y);
            uint2 ra = *(const uint2*)(H2 + (size_t)ea.x * 256 + ci);
            cs += ca;
            a0 += ca*b2f(ra.x&0xffffu); a1 += ca*b2f(ra.x>>16);
            a2 += ca*b2f(ra.y&0xffffu); a3 += ca*b2f(ra.y>>16);
        }
        uint2 rs = *(const uint2*)(H2 + (size_t)node * 256 + ci);
        const float sc = dn * dn, cv = cs + sc;
        float f0 = a0 + sc*b2f(rs.x&0xffffu) + cv*vv.x + bb.x;
        float f1 = a1 + sc*b2f(rs.x>>16)     + cv*vv.y + bb.y;
        float f2 = a2 + sc*b2f(rs.y&0xffffu) + cv*vv.z + bb.z;
        float f3 = a3 + sc*b2f(rs.y>>16)     + cv*vv.w + bb.w;
        uint2 o; o.x = packb(f0, f1); o.y = packb(f2, f3);
        *(uint2*)(OutB + (size_t)node * 256 + ci) = o;
        s0 += f0; q0 += f0*f0; s1 += f1; q1 += f1*f1;
        s2 += f2; q2 += f2*f2; s3 += f3; q3 += f3*f3;
    }
    ls[t] = 0.f; ls[256 + t] = 0.f;
    __syncthreads();
    atomicAdd(&ls[ci], s0);   atomicAdd(&ls[ci+1], s1);
    atomicAdd(&ls[ci+2], s2); atomicAdd(&ls[ci+3], s3);
    atomicAdd(&ls[256+ci], q0);   atomicAdd(&ls[256+ci+1], q1);
    atomicAdd(&ls[256+ci+2], q2); atomicAdd(&ls[256+ci+3], q3);
    __syncthreads();
    atomicAdd(&stats[t], ls[t]);
    atomicAdd(&stats[256 + t], ls[256 + t]);
}

// ---------------- virtual node update + v2_next = vx_new @ Wnext ----------------
// pool input: 8 spread copies of 256
__global__ void k_vx(const float* __restrict__ pool, const float* __restrict__ vx_old,
                     const float* __restrict__ vnW, const float* __restrict__ vnb,
                     const float* __restrict__ lng, const float* __restrict__ lnb,
                     float* __restrict__ vx_new,
                     const float* __restrict__ Wnext, int ncn, int npn,
                     float* __restrict__ v2n) {
    __shared__ float s[256];
    __shared__ float red[256];
    int t = threadIdx.x;
    float pv = 0.f;
#pragma unroll
    for (int r = 0; r < 8; r++) pv += pool[r * 256 + t];
    s[t] = pv + vx_old[t];
    __syncthreads();
    float y = vnb[t];
    for (int k = 0; k < 256; k++) y += s[k] * vnW[k * 256 + t];
    red[t] = y; __syncthreads();
    for (int off = 128; off > 0; off >>= 1) {
        if (t < off) red[t] += red[t + off];
        __syncthreads();
    }
    float mu = red[0] * (1.f / 256.f);
    __syncthreads();
    float d = y - mu;
    red[t] = d * d; __syncthreads();
    for (int off = 128; off > 0; off >>= 1) {
        if (t < off) red[t] += red[t + off];
        __syncthreads();
    }
    float var = red[0] * (1.f / 256.f);
    float v = fmaxf(d * rsqrtf(var + EPS) * lng[t] + lnb[t], 0.f);
    vx_new[t] = v;
    __syncthreads();
    s[t] = v;
    __syncthreads();
    float acc = 0.f;
    if (t < ncn) {
        for (int k = 0; k < 256; k++) acc += s[k] * Wnext[k * ncn + t];
    }
    if (t < npn) v2n[t] = acc;
}

// ---- layer-2 aggregation + (cs+dn^2)*v2 fold + log_softmax ----
__global__ __launch_bounds__(256) void k_agg2(const u16* __restrict__ H2,
                                              const int* __restrict__ row_start,
                                              const int* __restrict__ counts,
                                              const int2* __restrict__ edata,
                                              const float* __restrict__ dis,
                                              const float* __restrict__ bias,
                                              const float* __restrict__ v2,
                                              float* __restrict__ OutF) {
    const int t = threadIdx.x, wave = t >> 6, lane = t & 63;
    const int half = lane >> 5, hl = lane & 31;
    const bool gact = hl < 24;
    const bool cact = hl < 20;
    const int c0 = 2 * hl;
    float bb0 = 0.f, bb1 = 0.f, vv0 = 0.f, vv1 = 0.f;
    if (cact) {
        float2 bv = *(const float2*)(bias + c0); bb0 = bv.x; bb1 = bv.y;
        float2 vvv = *(const float2*)(v2 + c0);  vv0 = vvv.x; vv1 = vvv.y;
    }
    const int nbase = blockIdx.x * 16 + wave * 4;
    for (int i = 0; i < 4; i++) {
        const int node = nbase + i;
        const int beg = row_start[node], cnt = counts[node];
        const float dn = dis[node];
        float a0 = 0.f, a1 = 0.f, cs = 0.f;
        int e = half;
        for (; e + 6 < cnt; e += 8) {
            int2 ea = edata[beg+e],   eb = edata[beg+e+2];
            int2 ec = edata[beg+e+4], ed = edata[beg+e+6];
            float ca = __int_as_float(ea.y), cb = __int_as_float(eb.y);
            float cc = __int_as_float(ec.y), cd = __int_as_float(ed.y);
            u32 ra = 0, rb = 0, rc = 0, rd = 0;
            if (gact) {
                ra = *(const u32*)(H2 + (size_t)ea.x * COUTP + c0);
                rb = *(const u32*)(H2 + (size_t)eb.x * COUTP + c0);
                rc = *(const u32*)(H2 + (size_t)ec.x * COUTP + c0);
                rd = *(const u32*)(H2 + (size_t)ed.x * COUTP + c0);
            }
            cs += ca + cb + cc + cd;
            a0 += ca*b2f(ra&0xffffu) + cb*b2f(rb&0xffffu) + cc*b2f(rc&0xffffu) + cd*b2f(rd&0xffffu);
            a1 += ca*b2f(ra>>16)     + cb*b2f(rb>>16)     + cc*b2f(rc>>16)     + cd*b2f(rd>>16);
        }
        for (; e < cnt; e += 2) {
            int2 ea = edata[beg+e];
            float ca = __int_as_float(ea.y);
            u32 ra = gact ? *(const u32*)(H2 + (size_t)ea.x * COUTP + c0) : 0u;
            cs += ca;
            a0 += ca*b2f(ra&0xffffu); a1 += ca*b2f(ra>>16);
        }
        a0 += __shfl_xor(a0, 32);
        a1 += __shfl_xor(a1, 32);
        cs += __shfl_xor(cs, 32);
        const float sc = dn * dn;
        u32 rs_ = gact ? *(const u32*)(H2 + (size_t)node * COUTP + c0) : 0u;
        float h0 = a0 + sc*b2f(rs_&0xffffu) + (cs+sc)*vv0 + bb0;
        float h1 = a1 + sc*b2f(rs_>>16)     + (cs+sc)*vv1 + bb1;
        float m = cact ? fmaxf(h0, h1) : -3.0e38f;
#pragma unroll
        for (int off = 16; off > 0; off >>= 1) m = fmaxf(m, __shfl_xor(m, off));
        float ex = cact ? (expf(h0 - m) + expf(h1 - m)) : 0.f;
        float se = ex;
#pragma unroll
        for (int off = 16; off > 0; off >>= 1) se += __shfl_xor(se, off);
        float lg = logf(se);
        if (cact && half == 0) {
            float2 o = {h0 - m - lg, h1 - m - lg};
            *(float2*)(OutF + (size_t)node * COUT + c0) = o;
        }
    }
}

extern "C" void kernel_launch(void* const* d_in, const int* in_sizes, int n_in,
                              void* d_out, int out_size, void* d_ws, size_t ws_size,
                              hipStream_t stream) {
    const float* x   = (const float*)d_in[0];
    const int*   ei  = (const int*)d_in[1];
    const int*   esrc = ei;
    const int*   edst = ei + N_EDGES;
    const float* W0 = (const float*)d_in[2];  const float* b0 = (const float*)d_in[3];
    const float* W1 = (const float*)d_in[4];  const float* b1 = (const float*)d_in[5];
    const float* W2 = (const float*)d_in[6];  const float* b2 = (const float*)d_in[7];
    const float* bg0 = (const float*)d_in[8]; const float* bb0 = (const float*)d_in[9];
    const float* bg1 = (const float*)d_in[10]; const float* bb1 = (const float*)d_in[11];
    const float* vn_emb = (const float*)d_in[12];
    const float* vW0 = (const float*)d_in[13]; const float* vb0 = (const float*)d_in[14];
    const float* lg0 = (const float*)d_in[15]; const float* lb0 = (const float*)d_in[16];
    const float* vW1 = (const float*)d_in[17]; const float* vb1 = (const float*)d_in[18];
    const float* lg1 = (const float*)d_in[19]; const float* lb1 = (const float*)d_in[20];

    char* w = (char*)d_ws;
    auto alloc = [&](size_t bytes) { void* p = (void*)w; w += ((bytes + 255) / 256) * 256; return p; };
    u16* H2    = (u16*)alloc((size_t)N_NODES * 256 * 2);
    u16* OutB  = (u16*)alloc((size_t)N_NODES * 256 * 2);
    int2* edata = (int2*)alloc((size_t)N_EDGES * 8);
    int* counts = (int*)alloc((size_t)N_NODES * 4);
    int* rowst  = (int*)alloc((size_t)N_NODES * 4);
    int* cursor = (int*)alloc((size_t)N_NODES * 4);
    float* dis  = (float*)alloc((size_t)N_NODES * 4);
    u16* Wtb0 = (u16*)alloc(256 * 256 * 2);
    u16* Wtb1 = (u16*)alloc(256 * 256 * 2);
    u16* Wt2b = (u16*)alloc(COUTP * 256 * 2);
    int* scanblk = (int*)alloc(128 * 4);
    float* statsA = (float*)alloc(2560 * 4);   // sum[256], sq[256], pool[8*256]
    float* statsB = (float*)alloc(2560 * 4);
    float* vxA = (float*)alloc(256 * 4);
    float* vxB = (float*)alloc(256 * 4);
    float* v20 = (float*)alloc(256 * 4);
    float* v21 = (float*)alloc(256 * 4);
    float* v22 = (float*)alloc(64 * 4);
    (void)ws_size; (void)in_sizes; (void)n_in; (void)out_size;

    // ---- graph prep: degrees + CSR + packed edge data ----
    hipMemsetAsync(counts, 0, (size_t)N_NODES * 4, stream);
    hipMemsetAsync(statsA, 0, 2560 * 4, stream);
    hipMemsetAsync(statsB, 0, 2560 * 4, stream);
    k_count<<<(N_EDGES + 255) / 256, 256, 0, stream>>>(edst, counts);
    k_scan1<<<NSCAN_BLK, 256, 0, stream>>>(counts, rowst, scanblk);
    k_scan2<<<1, 128, 0, stream>>>(scanblk);
    k_scan3<<<(N_NODES + 255) / 256, 256, 0, stream>>>(rowst, scanblk, cursor, counts, dis);
    k_fill<<<(N_EDGES + 255) / 256, 256, 0, stream>>>(esrc, edst, cursor, edata, dis);

    // ---- weight prep ----
    k_wt3<<<512 + COUTP, 256, 0, stream>>>(W0, W1, W2, Wtb0, Wtb1, Wt2b);
    k_vecmat<<<1, 256, 0, stream>>>(vn_emb, W0, 256, 256, v20);

    const int gemmblk = (N_NODES + 63) / 64;
    const int aggblk = (N_NODES + 63) / 64;

    // ---- layer 0 ----
    k_gemm_f32a<<<gemmblk, 256, 0, stream>>>(x, Wtb0, H2);
    k_agg<<<aggblk, 256, 0, stream>>>(H2, rowst, counts, edata, dis, b0, v20, OutB, statsA);
    // ---- layer 1 (BN0+ReLU+pool fused into gemm A-staging) ----
    k_gemm_bn<<<gemmblk, 256, 0, stream>>>(OutB, statsA, bg0, bb0, Wtb1, H2, statsA + 512);
    k_vx<<<1, 256, 0, stream>>>(statsA + 512, vn_emb, vW0, vb0, lg0, lb0, vxA, W1, 256, 256, v21);
    k_agg<<<aggblk, 256, 0, stream>>>(H2, rowst, counts, edata, dis, b1, v21, OutB, statsB);
    // ---- layer 2 ----
    k_gemm2_bn<<<gemmblk, 256, 0, stream>>>(OutB, statsB, bg1, bb1, Wt2b, H2, statsB + 512);
    k_vx<<<1, 256, 0, stream>>>(statsB + 512, vxA, vW1, vb1, lg1, lb1, vxB, W2, COUT, COUTP, v22);
    k_agg2<<<N_NODES / 16, 256, 0, stream>>>(H2, rowst, counts, edata, dis, b2, v22, (float*)d_out);
}